// Round 1
// baseline (27638.794 us; speedup 1.0000x reference)
//
#include <hip/hip_runtime.h>
#include <math.h>

#define S_LEN 2048
#define HIDDEN 4096
#define NHEAD 32
#define D_NOPE 128
#define D_ROPE 64
#define D_V 128
#define D_QK 192
#define QRANK 1536
#define KVRANK 512
#define IDXH 16
#define IDXD 128
#define KSEL 1024

// ---------------------------------------------------------------------------
// Generic fp32 GEMM: C[M,N] = A[M,K] @ B[K,N], row-major.
// Requires M%64==0, K%16==0, K%4==0 for float4 A loads. N arbitrary (guarded).
// 64x64 tile, 256 threads, 4x4 micro-tile per thread.
// ---------------------------------------------------------------------------
__global__ __launch_bounds__(256) void gemm64(const float* __restrict__ A,
                                              const float* __restrict__ B,
                                              float* __restrict__ C,
                                              int M, int N, int K) {
    __shared__ float As[16][68];  // [k][m], padded so rows are 16B-aligned
    __shared__ float Bs[16][68];  // [k][n]
    const int tid = threadIdx.x;
    const int tx = tid & 15, ty = tid >> 4;
    const int bn = blockIdx.x * 64, bm = blockIdx.y * 64;

    float c[4][4] = {};

    const int ar = tid >> 2, ak = (tid & 3) << 2;    // A: row, k-quad
    const int bk = tid >> 4, bn4 = (tid & 15) << 2;  // B: k-row, n-quad

    for (int k0 = 0; k0 < K; k0 += 16) {
        // load A tile 64x16 (transposed into As[k][m])
        {
            const float4 v = *(const float4*)(A + (size_t)(bm + ar) * K + k0 + ak);
            As[ak + 0][ar] = v.x;
            As[ak + 1][ar] = v.y;
            As[ak + 2][ar] = v.z;
            As[ak + 3][ar] = v.w;
        }
        // load B tile 16x64
        {
            const float* bp = B + (size_t)(k0 + bk) * N + bn + bn4;
            if (bn + bn4 + 4 <= N) {
                *(float4*)&Bs[bk][bn4] = *(const float4*)bp;
            } else {
                for (int i = 0; i < 4; ++i)
                    Bs[bk][bn4 + i] = (bn + bn4 + i < N) ? bp[i] : 0.f;
            }
        }
        __syncthreads();
#pragma unroll
        for (int kk = 0; kk < 16; ++kk) {
            const float4 a4 = *(const float4*)&As[kk][ty * 4];
            const float4 b4 = *(const float4*)&Bs[kk][tx * 4];
            const float a[4] = {a4.x, a4.y, a4.z, a4.w};
            const float b[4] = {b4.x, b4.y, b4.z, b4.w};
#pragma unroll
            for (int i = 0; i < 4; ++i)
#pragma unroll
                for (int j = 0; j < 4; ++j) c[i][j] += a[i] * b[j];
        }
        __syncthreads();
    }
#pragma unroll
    for (int i = 0; i < 4; ++i) {
        const int m = bm + ty * 4 + i;
#pragma unroll
        for (int j = 0; j < 4; ++j) {
            const int n = bn + tx * 4 + j;
            if (n < N) C[(size_t)m * N + n] = c[i][j];
        }
    }
}

// ---------------------------------------------------------------------------
// RMSNorm: one block per row. out[row, 0:W] = in[row*stride + i]*rsqrt(mean+eps)*w[i]
// In-place safe (out==in, stride==W).
// ---------------------------------------------------------------------------
__global__ __launch_bounds__(256) void rmsnorm_kernel(const float* __restrict__ in,
                                                      const float* __restrict__ w,
                                                      float* __restrict__ out,
                                                      int W, int in_stride) {
    const int row = blockIdx.x;
    const int tid = threadIdx.x;
    const float* x = in + (size_t)row * in_stride;
    float ss = 0.f;
    for (int i = tid; i < W; i += 256) {
        float v = x[i];
        ss += v * v;
    }
    __shared__ float red[256];
    red[tid] = ss;
    __syncthreads();
    for (int s = 128; s > 0; s >>= 1) {
        if (tid < s) red[tid] += red[tid + s];
        __syncthreads();
    }
    const float scale = rsqrtf(red[0] / (float)W + 1e-5f);
    for (int i = tid; i < W; i += 256) out[(size_t)row * W + i] = x[i] * scale * w[i];
}

// ---------------------------------------------------------------------------
// RoPE (interleaved) on q_pe, in place. q layout: [S, NHEAD*192], pe at +128.
// ---------------------------------------------------------------------------
__global__ __launch_bounds__(256) void rope_q_kernel(float* __restrict__ q) {
    const int idx = blockIdx.x * 256 + threadIdx.x;
    if (idx >= S_LEN * NHEAD * (D_ROPE / 2)) return;
    const int i = idx & 31;
    const int h = (idx >> 5) & 31;
    const int s = idx >> 10;
    const float inv = __expf(-(float)i * (logf(10000.f) / 32.f));
    const float ang = (float)s * inv;
    const float cs = cosf(ang), sn = sinf(ang);
    float* p = q + (size_t)s * (NHEAD * D_QK) + h * D_QK + D_NOPE + 2 * i;
    const float x0 = p[0], x1 = p[1];
    p[0] = x0 * cs - x1 * sn;
    p[1] = x1 * cs + x0 * sn;
}

// RoPE on k_pe: read ckv[:, 512:576], write kpe[S,64]
__global__ __launch_bounds__(256) void rope_k_kernel(const float* __restrict__ ckv,
                                                     float* __restrict__ kpe) {
    const int idx = blockIdx.x * 256 + threadIdx.x;
    if (idx >= S_LEN * (D_ROPE / 2)) return;
    const int i = idx & 31;
    const int s = idx >> 5;
    const float inv = __expf(-(float)i * (logf(10000.f) / 32.f));
    const float ang = (float)s * inv;
    const float cs = cosf(ang), sn = sinf(ang);
    const float* p = ckv + (size_t)s * (KVRANK + D_ROPE) + KVRANK + 2 * i;
    const float x0 = p[0], x1 = p[1];
    float* o = kpe + (size_t)s * D_ROPE + 2 * i;
    o[0] = x0 * cs - x1 * sn;
    o[1] = x1 * cs + x0 * sn;
}

// ---------------------------------------------------------------------------
// Indexer scores, lower-triangular 64x64 tiles.
// iscore[q,k] = (1/sqrt(128)) * sum_n (iw[q,n]/4) * relu(iq[q,n,:].ik[k,:])
// ---------------------------------------------------------------------------
__global__ __launch_bounds__(256) void idx_score_kernel(const float* __restrict__ iq,
                                                        const float* __restrict__ ik,
                                                        const float* __restrict__ iw,
                                                        float* __restrict__ iscore) {
    const int kt = blockIdx.x, qt = blockIdx.y;
    if (kt > qt) return;
    const int q0 = qt * 64, k0 = kt * 64;
    __shared__ float iks[64][129];
    __shared__ float iqs[64][129];
    __shared__ float iws[64][16];
    const int tid = threadIdx.x;
    const int tx = tid & 15, ty = tid >> 4;

    for (int idx = tid; idx < 64 * 32; idx += 256) {
        const int r = idx >> 5, c4 = (idx & 31) << 2;
        const float4 v = *(const float4*)(ik + (size_t)(k0 + r) * IDXD + c4);
        iks[r][c4] = v.x; iks[r][c4 + 1] = v.y; iks[r][c4 + 2] = v.z; iks[r][c4 + 3] = v.w;
    }
    for (int idx = tid; idx < 64 * 16; idx += 256) {
        const int r = idx >> 4, c = idx & 15;
        iws[r][c] = iw[(size_t)(q0 + r) * IDXH + c] * 0.25f;  // IDX_H^-0.5
    }

    float acc[4][4] = {};
    for (int n = 0; n < IDXH; ++n) {
        __syncthreads();  // protect iqs from previous iteration readers (and iks first time)
        for (int idx = tid; idx < 64 * 32; idx += 256) {
            const int r = idx >> 5, c4 = (idx & 31) << 2;
            const float4 v = *(const float4*)(iq + (size_t)(q0 + r) * (IDXH * IDXD) + n * IDXD + c4);
            iqs[r][c4] = v.x; iqs[r][c4 + 1] = v.y; iqs[r][c4 + 2] = v.z; iqs[r][c4 + 3] = v.w;
        }
        __syncthreads();
        float dot[4][4] = {};
        for (int d = 0; d < IDXD; ++d) {
            float a[4], b[4];
#pragma unroll
            for (int i = 0; i < 4; ++i) a[i] = iqs[ty * 4 + i][d];
#pragma unroll
            for (int j = 0; j < 4; ++j) b[j] = iks[tx * 4 + j][d];
#pragma unroll
            for (int i = 0; i < 4; ++i)
#pragma unroll
                for (int j = 0; j < 4; ++j) dot[i][j] += a[i] * b[j];
        }
#pragma unroll
        for (int i = 0; i < 4; ++i) {
            const float w = iws[ty * 4 + i][n];
#pragma unroll
            for (int j = 0; j < 4; ++j) acc[i][j] += w * fmaxf(dot[i][j], 0.f);
        }
    }
    const float sc = 0.08838834764831845f;  // 1/sqrt(128)
#pragma unroll
    for (int i = 0; i < 4; ++i)
#pragma unroll
        for (int j = 0; j < 4; ++j) {
            const int qq = q0 + ty * 4 + i, kk = k0 + tx * 4 + j;
            iscore[(size_t)qq * S_LEN + kk] = acc[i][j] * sc;
        }
}

// ---------------------------------------------------------------------------
// Exact top-K per row. One block per query row.
// Rows with <=K causal keys: all causal selected. Else binary-search the K-th
// largest (sortable-uint) and tie-fill in increasing index order (matches
// jax.lax.top_k lowest-index tie-break).
// ---------------------------------------------------------------------------
__global__ __launch_bounds__(256) void topk_kernel(const float* __restrict__ iscore,
                                                   unsigned char* __restrict__ mask) {
    const int q = blockIdx.x;
    const int tid = threadIdx.x;
    const int nk = q + 1;
    unsigned char* mrow = mask + (size_t)q * S_LEN;
    if (nk <= KSEL) {
        for (int k = tid; k < S_LEN; k += 256) mrow[k] = (k <= q) ? 1 : 0;
        return;
    }
    __shared__ unsigned int uv[S_LEN];
    const float* srow = iscore + (size_t)q * S_LEN;
    for (int k = tid; k < nk; k += 256) {
        unsigned int b = __float_as_uint(srow[k]);
        uv[k] = (b & 0x80000000u) ? ~b : (b | 0x80000000u);
    }
    __syncthreads();
    __shared__ int cnt;
    unsigned int lo = 0u, hi = 0xFFFFFFFFu;
    while (lo < hi) {
        const unsigned long long range = (unsigned long long)(hi - lo);
        const unsigned int mid = lo + (unsigned int)((range + 1ull) >> 1);
        if (tid == 0) cnt = 0;
        __syncthreads();
        int c = 0;
        for (int k = tid; k < nk; k += 256) c += (uv[k] >= mid) ? 1 : 0;
        atomicAdd(&cnt, c);
        __syncthreads();
        const int total = cnt;
        __syncthreads();
        if (total >= KSEL) lo = mid; else hi = mid - 1;
    }
    const unsigned int T = lo;
    if (tid == 0) cnt = 0;
    __syncthreads();
    {
        int c = 0;
        for (int k = tid; k < nk; k += 256) c += (uv[k] > T) ? 1 : 0;
        atomicAdd(&cnt, c);
    }
    __syncthreads();
    const int r = KSEL - cnt;  // how many ==T to take, lowest index first
    for (int k = tid; k < S_LEN; k += 256) {
        unsigned char mv = 0;
        if (k < nk) {
            const unsigned int u = uv[k];
            if (u > T) {
                mv = 1;
            } else if (u == T) {
                int rank = 0;
                for (int j = 0; j < k; ++j) rank += (uv[j] == T) ? 1 : 0;
                mv = (rank < r) ? 1 : 0;
            }
        }
        mrow[k] = mv;
    }
}

// ---------------------------------------------------------------------------
// Attention: one block (256 thr) per (q, h). Masked scores -> softmax -> PV.
// q: [S, 32*192]; kv: [S, 32*256] (k_nope at h*256, v at h*256+128); kpe: [S,64]
// out: [S, 32*128]
// ---------------------------------------------------------------------------
__global__ __launch_bounds__(256) void attn_kernel(const float* __restrict__ q,
                                                   const float* __restrict__ kv,
                                                   const float* __restrict__ kpe,
                                                   const unsigned char* __restrict__ mask,
                                                   float* __restrict__ out) {
    const int qi = blockIdx.x;
    const int h = blockIdx.y;
    const int tid = threadIdx.x;
    const int nk = qi + 1;

    __shared__ float qv[D_QK];
    __shared__ float sc[S_LEN];
    __shared__ float red[256];

    for (int d = tid; d < D_QK; d += 256) qv[d] = q[(size_t)qi * (NHEAD * D_QK) + h * D_QK + d];
    __syncthreads();

    const float scale = 0.07216878364870323f;  // 1/sqrt(192)
    const unsigned char* mrow = mask + (size_t)qi * S_LEN;
    for (int k = tid; k < nk; k += 256) {
        float s;
        if (mrow[k]) {
            const float4* kr4 = (const float4*)(kv + (size_t)k * (NHEAD * 256) + h * 256);
            float acc = 0.f;
#pragma unroll
            for (int d4 = 0; d4 < 32; ++d4) {
                const float4 kk4 = kr4[d4];
                acc += qv[d4 * 4] * kk4.x + qv[d4 * 4 + 1] * kk4.y +
                       qv[d4 * 4 + 2] * kk4.z + qv[d4 * 4 + 3] * kk4.w;
            }
            const float4* pr4 = (const float4*)(kpe + (size_t)k * D_ROPE);
#pragma unroll
            for (int d4 = 0; d4 < 16; ++d4) {
                const float4 kk4 = pr4[d4];
                acc += qv[128 + d4 * 4] * kk4.x + qv[128 + d4 * 4 + 1] * kk4.y +
                       qv[128 + d4 * 4 + 2] * kk4.z + qv[128 + d4 * 4 + 3] * kk4.w;
            }
            s = acc * scale;
        } else {
            s = -INFINITY;
        }
        sc[k] = s;
    }
    __syncthreads();

    // block max
    float m = -INFINITY;
    for (int k = tid; k < nk; k += 256) m = fmaxf(m, sc[k]);
    red[tid] = m;
    __syncthreads();
    for (int s2 = 128; s2 > 0; s2 >>= 1) {
        if (tid < s2) red[tid] = fmaxf(red[tid], red[tid + s2]);
        __syncthreads();
    }
    m = red[0];
    __syncthreads();

    // exp + sum
    float sum = 0.f;
    for (int k = tid; k < nk; k += 256) {
        const float p = expf(sc[k] - m);
        sc[k] = p;
        sum += p;
    }
    red[tid] = sum;
    __syncthreads();
    for (int s2 = 128; s2 > 0; s2 >>= 1) {
        if (tid < s2) red[tid] += red[tid + s2];
        __syncthreads();
    }
    const float rinv = 1.f / red[0];
    __syncthreads();

    // PV: 2 halves of k-range, 128 dims each
    const int half = tid >> 7, d = tid & 127;
    float acc = 0.f;
    for (int k = half; k < nk; k += 2) {
        const float p = sc[k];
        if (p > 0.f) acc += p * kv[(size_t)k * (NHEAD * 256) + h * 256 + 128 + d];
    }
    red[tid] = acc;
    __syncthreads();
    if (tid < 128)
        out[(size_t)qi * (NHEAD * D_V) + h * D_V + tid] = (red[tid] + red[tid + 128]) * rinv;
}

// ---------------------------------------------------------------------------
extern "C" void kernel_launch(void* const* d_in, const int* in_sizes, int n_in,
                              void* d_out, int out_size, void* d_ws, size_t ws_size,
                              hipStream_t stream) {
    const float* hidden        = (const float*)d_in[0];
    const float* q_a_w         = (const float*)d_in[1];
    const float* q_a_norm_w    = (const float*)d_in[2];
    const float* q_b_w         = (const float*)d_in[3];
    const float* kv_a_w        = (const float*)d_in[4];
    const float* kv_a_norm_w   = (const float*)d_in[5];
    const float* kv_b_w        = (const float*)d_in[6];
    const float* o_w           = (const float*)d_in[7];
    const float* idx_wq_w      = (const float*)d_in[8];
    const float* idx_wk_w      = (const float*)d_in[9];
    const float* idx_weights_w = (const float*)d_in[10];
    float* out = (float*)d_out;

    char* ws = (char*)d_ws;
    size_t off = 0;
    auto alloc = [&](size_t bytes) -> void* {
        void* p = ws + off;
        off += (bytes + 255) & ~(size_t)255;
        return p;
    };
    float* qa    = (float*)alloc((size_t)S_LEN * QRANK * 4);            // q latent (norm in-place)
    float* qbuf  = (float*)alloc((size_t)S_LEN * NHEAD * D_QK * 4);     // q (nope+pe)
    float* ckv   = (float*)alloc((size_t)S_LEN * (KVRANK + D_ROPE) * 4);
    float* kvn   = (float*)alloc((size_t)S_LEN * KVRANK * 4);
    float* kv    = (float*)alloc((size_t)S_LEN * NHEAD * 256 * 4);      // k_nope + v
    float* kpe   = (float*)alloc((size_t)S_LEN * D_ROPE * 4);
    float* iq    = (float*)alloc((size_t)S_LEN * IDXH * IDXD * 4);
    float* ik    = (float*)alloc((size_t)S_LEN * IDXD * 4);
    float* iww   = (float*)alloc((size_t)S_LEN * IDXH * 4);
    float* iscr  = (float*)alloc((size_t)S_LEN * S_LEN * 4);
    float* aout  = (float*)alloc((size_t)S_LEN * NHEAD * D_V * 4);
    unsigned char* mask = (unsigned char*)alloc((size_t)S_LEN * S_LEN);
    (void)ws_size; (void)in_sizes; (void)n_in; (void)out_size;

    const dim3 blk(256);

    // q path
    gemm64<<<dim3(QRANK / 64, S_LEN / 64), blk, 0, stream>>>(hidden, q_a_w, qa, S_LEN, QRANK, HIDDEN);
    rmsnorm_kernel<<<S_LEN, blk, 0, stream>>>(qa, q_a_norm_w, qa, QRANK, QRANK);
    gemm64<<<dim3(NHEAD * D_QK / 64, S_LEN / 64), blk, 0, stream>>>(qa, q_b_w, qbuf, S_LEN, NHEAD * D_QK, QRANK);

    // kv path
    gemm64<<<dim3((KVRANK + D_ROPE + 63) / 64, S_LEN / 64), blk, 0, stream>>>(hidden, kv_a_w, ckv, S_LEN, KVRANK + D_ROPE, HIDDEN);
    rmsnorm_kernel<<<S_LEN, blk, 0, stream>>>(ckv, kv_a_norm_w, kvn, KVRANK, KVRANK + D_ROPE);
    gemm64<<<dim3(NHEAD * 256 / 64, S_LEN / 64), blk, 0, stream>>>(kvn, kv_b_w, kv, S_LEN, NHEAD * 256, KVRANK);

    // rope
    rope_q_kernel<<<(S_LEN * NHEAD * 32 + 255) / 256, blk, 0, stream>>>(qbuf);
    rope_k_kernel<<<(S_LEN * 32 + 255) / 256, blk, 0, stream>>>(ckv, kpe);

    // indexer
    gemm64<<<dim3(IDXH * IDXD / 64, S_LEN / 64), blk, 0, stream>>>(hidden, idx_wq_w, iq, S_LEN, IDXH * IDXD, HIDDEN);
    gemm64<<<dim3(IDXD / 64, S_LEN / 64), blk, 0, stream>>>(hidden, idx_wk_w, ik, S_LEN, IDXD, HIDDEN);
    gemm64<<<dim3(1, S_LEN / 64), blk, 0, stream>>>(hidden, idx_weights_w, iww, S_LEN, IDXH, HIDDEN);
    idx_score_kernel<<<dim3(S_LEN / 64, S_LEN / 64), blk, 0, stream>>>(iq, ik, iww, iscr);
    topk_kernel<<<S_LEN, blk, 0, stream>>>(iscr, mask);

    // attention
    attn_kernel<<<dim3(S_LEN, NHEAD), blk, 0, stream>>>(qbuf, kv, kpe, mask, aout);

    // output projection
    gemm64<<<dim3(HIDDEN / 64, S_LEN / 64), blk, 0, stream>>>(aout, o_w, out, S_LEN, HIDDEN, HIDDEN);
}

// Round 2
// 4501.331 us; speedup vs baseline: 6.1401x; 6.1401x over previous
//
#include <hip/hip_runtime.h>
#include <math.h>

#define S_LEN 2048
#define HIDDEN 4096
#define NHEAD 32
#define D_NOPE 128
#define D_ROPE 64
#define D_V 128
#define D_QK 192
#define QRANK 1536
#define KVRANK 512
#define IDXH 16
#define IDXD 128
#define KSEL 1024

typedef __attribute__((ext_vector_type(8))) short bf16x8;
typedef __attribute__((ext_vector_type(4))) float f32x4;

__device__ __forceinline__ unsigned short f2b(float f) {
    union { float f; unsigned int u; } x; x.f = f;
    unsigned int r = x.u + 0x7FFFu + ((x.u >> 16) & 1u);
    return (unsigned short)(r >> 16);
}

// ---------------------------------------------------------------------------
// Generic fp32 GEMM: C[M,N] = A[M,K] @ B[K,N], row-major. 64x64 tile.
// ---------------------------------------------------------------------------
__global__ __launch_bounds__(256) void gemm64(const float* __restrict__ A,
                                              const float* __restrict__ B,
                                              float* __restrict__ C,
                                              int M, int N, int K) {
    __shared__ float As[16][68];
    __shared__ float Bs[16][68];
    const int tid = threadIdx.x;
    const int tx = tid & 15, ty = tid >> 4;
    const int bn = blockIdx.x * 64, bm = blockIdx.y * 64;

    float c[4][4] = {};

    const int ar = tid >> 2, ak = (tid & 3) << 2;
    const int bk = tid >> 4, bn4 = (tid & 15) << 2;

    for (int k0 = 0; k0 < K; k0 += 16) {
        {
            const float4 v = *(const float4*)(A + (size_t)(bm + ar) * K + k0 + ak);
            As[ak + 0][ar] = v.x;
            As[ak + 1][ar] = v.y;
            As[ak + 2][ar] = v.z;
            As[ak + 3][ar] = v.w;
        }
        {
            const float* bp = B + (size_t)(k0 + bk) * N + bn + bn4;
            if (bn + bn4 + 4 <= N) {
                *(float4*)&Bs[bk][bn4] = *(const float4*)bp;
            } else {
                for (int i = 0; i < 4; ++i)
                    Bs[bk][bn4 + i] = (bn + bn4 + i < N) ? bp[i] : 0.f;
            }
        }
        __syncthreads();
#pragma unroll
        for (int kk = 0; kk < 16; ++kk) {
            const float4 a4 = *(const float4*)&As[kk][ty * 4];
            const float4 b4 = *(const float4*)&Bs[kk][tx * 4];
            const float a[4] = {a4.x, a4.y, a4.z, a4.w};
            const float b[4] = {b4.x, b4.y, b4.z, b4.w};
#pragma unroll
            for (int i = 0; i < 4; ++i)
#pragma unroll
                for (int j = 0; j < 4; ++j) c[i][j] += a[i] * b[j];
        }
        __syncthreads();
    }
#pragma unroll
    for (int i = 0; i < 4; ++i) {
        const int m = bm + ty * 4 + i;
#pragma unroll
        for (int j = 0; j < 4; ++j) {
            const int n = bn + tx * 4 + j;
            if (n < N) C[(size_t)m * N + n] = c[i][j];
        }
    }
}

// ---------------------------------------------------------------------------
__global__ __launch_bounds__(256) void rmsnorm_kernel(const float* __restrict__ in,
                                                      const float* __restrict__ w,
                                                      float* __restrict__ out,
                                                      int W, int in_stride) {
    const int row = blockIdx.x;
    const int tid = threadIdx.x;
    const float* x = in + (size_t)row * in_stride;
    float ss = 0.f;
    for (int i = tid; i < W; i += 256) {
        float v = x[i];
        ss += v * v;
    }
    __shared__ float red[256];
    red[tid] = ss;
    __syncthreads();
    for (int s = 128; s > 0; s >>= 1) {
        if (tid < s) red[tid] += red[tid + s];
        __syncthreads();
    }
    const float scale = rsqrtf(red[0] / (float)W + 1e-5f);
    for (int i = tid; i < W; i += 256) out[(size_t)row * W + i] = x[i] * scale * w[i];
}

// ---------------------------------------------------------------------------
__global__ __launch_bounds__(256) void rope_q_kernel(float* __restrict__ q) {
    const int idx = blockIdx.x * 256 + threadIdx.x;
    if (idx >= S_LEN * NHEAD * (D_ROPE / 2)) return;
    const int i = idx & 31;
    const int h = (idx >> 5) & 31;
    const int s = idx >> 10;
    const float inv = __expf(-(float)i * (logf(10000.f) / 32.f));
    const float ang = (float)s * inv;
    const float cs = cosf(ang), sn = sinf(ang);
    float* p = q + (size_t)s * (NHEAD * D_QK) + h * D_QK + D_NOPE + 2 * i;
    const float x0 = p[0], x1 = p[1];
    p[0] = x0 * cs - x1 * sn;
    p[1] = x1 * cs + x0 * sn;
}

__global__ __launch_bounds__(256) void rope_k_kernel(const float* __restrict__ ckv,
                                                     float* __restrict__ kpe) {
    const int idx = blockIdx.x * 256 + threadIdx.x;
    if (idx >= S_LEN * (D_ROPE / 2)) return;
    const int i = idx & 31;
    const int s = idx >> 5;
    const float inv = __expf(-(float)i * (logf(10000.f) / 32.f));
    const float ang = (float)s * inv;
    const float cs = cosf(ang), sn = sinf(ang);
    const float* p = ckv + (size_t)s * (KVRANK + D_ROPE) + KVRANK + 2 * i;
    const float x0 = p[0], x1 = p[1];
    float* o = kpe + (size_t)s * D_ROPE + 2 * i;
    o[0] = x0 * cs - x1 * sn;
    o[1] = x1 * cs + x0 * sn;
}

// ---------------------------------------------------------------------------
// Indexer scores (unchanged this round)
// ---------------------------------------------------------------------------
__global__ __launch_bounds__(256) void idx_score_kernel(const float* __restrict__ iq,
                                                        const float* __restrict__ ik,
                                                        const float* __restrict__ iw,
                                                        float* __restrict__ iscore) {
    const int kt = blockIdx.x, qt = blockIdx.y;
    if (kt > qt) return;
    const int q0 = qt * 64, k0 = kt * 64;
    __shared__ float iks[64][129];
    __shared__ float iqs[64][129];
    __shared__ float iws[64][16];
    const int tid = threadIdx.x;
    const int tx = tid & 15, ty = tid >> 4;

    for (int idx = tid; idx < 64 * 32; idx += 256) {
        const int r = idx >> 5, c4 = (idx & 31) << 2;
        const float4 v = *(const float4*)(ik + (size_t)(k0 + r) * IDXD + c4);
        iks[r][c4] = v.x; iks[r][c4 + 1] = v.y; iks[r][c4 + 2] = v.z; iks[r][c4 + 3] = v.w;
    }
    for (int idx = tid; idx < 64 * 16; idx += 256) {
        const int r = idx >> 4, c = idx & 15;
        iws[r][c] = iw[(size_t)(q0 + r) * IDXH + c] * 0.25f;
    }

    float acc[4][4] = {};
    for (int n = 0; n < IDXH; ++n) {
        __syncthreads();
        for (int idx = tid; idx < 64 * 32; idx += 256) {
            const int r = idx >> 5, c4 = (idx & 31) << 2;
            const float4 v = *(const float4*)(iq + (size_t)(q0 + r) * (IDXH * IDXD) + n * IDXD + c4);
            iqs[r][c4] = v.x; iqs[r][c4 + 1] = v.y; iqs[r][c4 + 2] = v.z; iqs[r][c4 + 3] = v.w;
        }
        __syncthreads();
        float dot[4][4] = {};
        for (int d = 0; d < IDXD; ++d) {
            float a[4], b[4];
#pragma unroll
            for (int i = 0; i < 4; ++i) a[i] = iqs[ty * 4 + i][d];
#pragma unroll
            for (int j = 0; j < 4; ++j) b[j] = iks[tx * 4 + j][d];
#pragma unroll
            for (int i = 0; i < 4; ++i)
#pragma unroll
                for (int j = 0; j < 4; ++j) dot[i][j] += a[i] * b[j];
        }
#pragma unroll
        for (int i = 0; i < 4; ++i) {
            const float w = iws[ty * 4 + i][n];
#pragma unroll
            for (int j = 0; j < 4; ++j) acc[i][j] += w * fmaxf(dot[i][j], 0.f);
        }
    }
    const float sc = 0.08838834764831845f;
#pragma unroll
    for (int i = 0; i < 4; ++i)
#pragma unroll
        for (int j = 0; j < 4; ++j) {
            const int qq = q0 + ty * 4 + i, kk = k0 + tx * 4 + j;
            iscore[(size_t)qq * S_LEN + kk] = acc[i][j] * sc;
        }
}

// ---------------------------------------------------------------------------
// Exact top-K per row (unchanged)
// ---------------------------------------------------------------------------
__global__ __launch_bounds__(256) void topk_kernel(const float* __restrict__ iscore,
                                                   unsigned char* __restrict__ mask) {
    const int q = blockIdx.x;
    const int tid = threadIdx.x;
    const int nk = q + 1;
    unsigned char* mrow = mask + (size_t)q * S_LEN;
    if (nk <= KSEL) {
        for (int k = tid; k < S_LEN; k += 256) mrow[k] = (k <= q) ? 1 : 0;
        return;
    }
    __shared__ unsigned int uv[S_LEN];
    const float* srow = iscore + (size_t)q * S_LEN;
    for (int k = tid; k < nk; k += 256) {
        unsigned int b = __float_as_uint(srow[k]);
        uv[k] = (b & 0x80000000u) ? ~b : (b | 0x80000000u);
    }
    __syncthreads();
    __shared__ int cnt;
    unsigned int lo = 0u, hi = 0xFFFFFFFFu;
    while (lo < hi) {
        const unsigned long long range = (unsigned long long)(hi - lo);
        const unsigned int mid = lo + (unsigned int)((range + 1ull) >> 1);
        if (tid == 0) cnt = 0;
        __syncthreads();
        int c = 0;
        for (int k = tid; k < nk; k += 256) c += (uv[k] >= mid) ? 1 : 0;
        atomicAdd(&cnt, c);
        __syncthreads();
        const int total = cnt;
        __syncthreads();
        if (total >= KSEL) lo = mid; else hi = mid - 1;
    }
    const unsigned int T = lo;
    if (tid == 0) cnt = 0;
    __syncthreads();
    {
        int c = 0;
        for (int k = tid; k < nk; k += 256) c += (uv[k] > T) ? 1 : 0;
        atomicAdd(&cnt, c);
    }
    __syncthreads();
    const int r = KSEL - cnt;
    for (int k = tid; k < S_LEN; k += 256) {
        unsigned char mv = 0;
        if (k < nk) {
            const unsigned int u = uv[k];
            if (u > T) {
                mv = 1;
            } else if (u == T) {
                int rank = 0;
                for (int j = 0; j < k; ++j) rank += (uv[j] == T) ? 1 : 0;
                mv = (rank < r) ? 1 : 0;
            }
        }
        mrow[k] = mv;
    }
}

// ---------------------------------------------------------------------------
// Attention prep: pack q/k to bf16 per-head layout; transpose V to bf16.
// ---------------------------------------------------------------------------
#define QK_SCALE 0.07216878364870323f  // 1/sqrt(192)

// qb16[h][s][192] = qbuf[s][h*192+d] * QK_SCALE
__global__ __launch_bounds__(256) void pack_q_kernel(const float* __restrict__ qbuf,
                                                     unsigned short* __restrict__ qb16) {
    const int idx = blockIdx.x * 256 + threadIdx.x;
    const int h = idx / (S_LEN * D_QK);
    const int rem = idx - h * (S_LEN * D_QK);
    const int s = rem / D_QK;
    const int d = rem - s * D_QK;
    qb16[idx] = f2b(qbuf[(size_t)s * (NHEAD * D_QK) + h * D_QK + d] * QK_SCALE);
}

// kb16[h][s][192] = {kv[s][h*256+d] (d<128), kpe[s][d-128] (d>=128)}
__global__ __launch_bounds__(256) void pack_k_kernel(const float* __restrict__ kv,
                                                     const float* __restrict__ kpe,
                                                     unsigned short* __restrict__ kb16) {
    const int idx = blockIdx.x * 256 + threadIdx.x;
    const int h = idx / (S_LEN * D_QK);
    const int rem = idx - h * (S_LEN * D_QK);
    const int s = rem / D_QK;
    const int d = rem - s * D_QK;
    const float v = (d < 128) ? kv[(size_t)s * (NHEAD * 256) + h * 256 + d]
                              : kpe[(size_t)s * D_ROPE + (d - 128)];
    kb16[idx] = f2b(v);
}

// vT[h][d (128)][s (2048)] = kv[s][h*256+128+d], bf16, tiled transpose
__global__ __launch_bounds__(256) void pack_vT_kernel(const float* __restrict__ kv,
                                                      unsigned short* __restrict__ vT) {
    const int st = blockIdx.x, h = blockIdx.y;
    const int s0 = st * 64;
    __shared__ unsigned short lv[64][130];
    const int tid = threadIdx.x;
#pragma unroll
    for (int it = 0; it < 32; ++it) {
        const int idx = tid + it * 256;
        const int sl = idx >> 7, d = idx & 127;
        lv[sl][d] = f2b(kv[(size_t)(s0 + sl) * (NHEAD * 256) + h * 256 + 128 + d]);
    }
    __syncthreads();
#pragma unroll
    for (int it = 0; it < 32; ++it) {
        const int idx = tid + it * 256;
        const int d = idx >> 6, sl = idx & 63;
        vT[(size_t)(h * 128 + d) * S_LEN + s0 + sl] = lv[sl][d];
    }
}

// ---------------------------------------------------------------------------
// MFMA flash attention. Block = (q-tile of 64, head); 4 waves (16 q rows each).
// Iterates 32-key tiles; mask (topk&causal) applied per element.
// LDS: K 32x384B swizzled @0; Vt 128 rows x 80B @12288; P 4x16x80B @22528;
//      mask 64x32 @27648. Total 29696 B.
// ---------------------------------------------------------------------------
#define ALD_K 0
#define ALD_V 12288
#define ALD_P 22528
#define ALD_M 27648

__global__ __launch_bounds__(256) void attn_mfma_kernel(
    const unsigned short* __restrict__ qb16,
    const unsigned short* __restrict__ kb16,
    const unsigned short* __restrict__ vT,
    const unsigned char* __restrict__ mask,
    float* __restrict__ aout) {
    __shared__ __align__(16) unsigned char smem[29696];
    const int qt = blockIdx.x, h = blockIdx.y;
    const int q0 = qt * 64;
    const int tid = threadIdx.x;
    const int w = tid >> 6, lane = tid & 63;
    const int g = lane >> 4, lr = lane & 15;

    // Q fragments (A-layout): lane holds Q[q0+w*16+lr][c*32 + g*8 + e]
    bf16x8 qf[6];
    {
        const unsigned short* qrow = qb16 + ((size_t)h * S_LEN + q0 + w * 16 + lr) * D_QK;
#pragma unroll
        for (int c = 0; c < 6; ++c) qf[c] = *(const bf16x8*)(qrow + c * 32 + g * 8);
    }

    f32x4 O[8];
#pragma unroll
    for (int db = 0; db < 8; ++db) O[db] = (f32x4){0.f, 0.f, 0.f, 0.f};
    float mS[4] = {-INFINITY, -INFINITY, -INFINITY, -INFINITY};
    float lS[4] = {0.f, 0.f, 0.f, 0.f};

    const int nt = (q0 + 64) >> 5;
    const unsigned char* kbase = (const unsigned char*)(kb16 + (size_t)h * S_LEN * D_QK);
    const unsigned char* vbase = (const unsigned char*)(vT + (size_t)h * 128 * S_LEN);
    const unsigned char* mbase = mask + (size_t)q0 * S_LEN;
    unsigned short* Pb = (unsigned short*)(smem + ALD_P + w * 1280);

    for (int t = 0; t < nt; ++t) {
        const int k0 = t << 5;
        // ---- stage K tile (32 rows x 384B), XOR-swizzled ----
#pragma unroll
        for (int it = 0; it < 3; ++it) {
            const int j = tid + it * 256;
            const int row = j / 24, cs = j - row * 24;
            const int colb = cs << 4;
            const uint4 v = *(const uint4*)(kbase + (size_t)(k0 + row) * 384 + colb);
            *(uint4*)(smem + ALD_K + row * 384 + (colb ^ ((row & 7) << 4))) = v;
        }
        // ---- stage Vt tile (128 rows x 64B data, 80B stride) ----
#pragma unroll
        for (int it = 0; it < 2; ++it) {
            const int j = tid + it * 256;
            const int d = j >> 2, slot = j & 3;
            const uint4 v = *(const uint4*)(vbase + ((size_t)d * S_LEN + k0) * 2 + slot * 16);
            *(uint4*)(smem + ALD_V + d * 80 + slot * 16) = v;
        }
        // ---- stage mask tile (64x32 bytes) ----
        {
            const int qr = tid >> 2, kc = (tid & 3) << 3;
            const uint2 v = *(const uint2*)(mbase + (size_t)qr * S_LEN + k0 + kc);
            *(uint2*)(smem + ALD_M + qr * 32 + kc) = v;
        }
        __syncthreads();

        // ---- QK^T: S[16q][32k] per wave ----
        f32x4 a0 = (f32x4){0.f, 0.f, 0.f, 0.f};
        f32x4 a1 = (f32x4){0.f, 0.f, 0.f, 0.f};
#pragma unroll
        for (int c = 0; c < 6; ++c) {
            const int colb = c * 64 + g * 16;
            const bf16x8 b0 = *(const bf16x8*)(smem + ALD_K + lr * 384 + (colb ^ ((lr & 7) << 4)));
            const bf16x8 b1 = *(const bf16x8*)(smem + ALD_K + (16 + lr) * 384 + (colb ^ ((lr & 7) << 4)));
            a0 = __builtin_amdgcn_mfma_f32_16x16x32_bf16(qf[c], b0, a0, 0, 0, 0);
            a1 = __builtin_amdgcn_mfma_f32_16x16x32_bf16(qf[c], b1, a1, 0, 0, 0);
        }

        // ---- online softmax (C-layout: lane owns rows g*4+r, col lr / lr+16) ----
        float corr[4];
#pragma unroll
        for (int r = 0; r < 4; ++r) {
            const int qrl = w * 16 + g * 4 + r;
            const float s0 = smem[ALD_M + qrl * 32 + lr] ? a0[r] : -INFINITY;
            const float s1 = smem[ALD_M + qrl * 32 + 16 + lr] ? a1[r] : -INFINITY;
            float tm = fmaxf(s0, s1);
            tm = fmaxf(tm, __shfl_xor(tm, 1));
            tm = fmaxf(tm, __shfl_xor(tm, 2));
            tm = fmaxf(tm, __shfl_xor(tm, 4));
            tm = fmaxf(tm, __shfl_xor(tm, 8));
            const float mn = fmaxf(mS[r], tm);
            const float co = (mS[r] > -INFINITY) ? __expf(mS[r] - mn) : 0.f;
            const float p0 = (s0 > -INFINITY) ? __expf(s0 - mn) : 0.f;
            const float p1 = (s1 > -INFINITY) ? __expf(s1 - mn) : 0.f;
            float rs = p0 + p1;
            rs += __shfl_xor(rs, 1);
            rs += __shfl_xor(rs, 2);
            rs += __shfl_xor(rs, 4);
            rs += __shfl_xor(rs, 8);
            lS[r] = lS[r] * co + rs;
            mS[r] = mn;
            corr[r] = co;
            Pb[(g * 4 + r) * 40 + lr] = f2b(p0);
            Pb[(g * 4 + r) * 40 + 16 + lr] = f2b(p1);
        }
#pragma unroll
        for (int db = 0; db < 8; ++db) {
            O[db][0] *= corr[0];
            O[db][1] *= corr[1];
            O[db][2] *= corr[2];
            O[db][3] *= corr[3];
        }

        // ensure P writes landed before in-wave re-read (rule 18)
        asm volatile("s_waitcnt lgkmcnt(0)" ::: "memory");
        __builtin_amdgcn_sched_barrier(0);

        // ---- PV: O[16q][128d] += P[16q][32k] * V[32k][128d] ----
        const bf16x8 pA = *(const bf16x8*)((const unsigned char*)Pb + lr * 80 + g * 16);
#pragma unroll
        for (int db = 0; db < 8; ++db) {
            const bf16x8 bV = *(const bf16x8*)(smem + ALD_V + (db * 16 + lr) * 80 + g * 16);
            O[db] = __builtin_amdgcn_mfma_f32_16x16x32_bf16(pA, bV, O[db], 0, 0, 0);
        }
        __syncthreads();
    }

    // ---- finalize ----
#pragma unroll
    for (int r = 0; r < 4; ++r) {
        const float inv = (lS[r] > 0.f) ? 1.f / lS[r] : 0.f;
        const int qg = q0 + w * 16 + g * 4 + r;
        float* orow = aout + (size_t)qg * (NHEAD * D_V) + h * D_V;
#pragma unroll
        for (int db = 0; db < 8; ++db) orow[db * 16 + lr] = O[db][r] * inv;
    }
}

// ---------------------------------------------------------------------------
extern "C" void kernel_launch(void* const* d_in, const int* in_sizes, int n_in,
                              void* d_out, int out_size, void* d_ws, size_t ws_size,
                              hipStream_t stream) {
    const float* hidden        = (const float*)d_in[0];
    const float* q_a_w         = (const float*)d_in[1];
    const float* q_a_norm_w    = (const float*)d_in[2];
    const float* q_b_w         = (const float*)d_in[3];
    const float* kv_a_w        = (const float*)d_in[4];
    const float* kv_a_norm_w   = (const float*)d_in[5];
    const float* kv_b_w        = (const float*)d_in[6];
    const float* o_w           = (const float*)d_in[7];
    const float* idx_wq_w      = (const float*)d_in[8];
    const float* idx_wk_w      = (const float*)d_in[9];
    const float* idx_weights_w = (const float*)d_in[10];
    float* out = (float*)d_out;

    char* ws = (char*)d_ws;
    // --- static layout with liveness-based overlays (total ~212 MB) ---
    float* qbuf = (float*)(ws + 0);                       // [S][32*192]   50331648 B
    float* kv   = (float*)(ws + 50331648);                // [S][32*256]   67108864 B
    float* kpe  = (float*)(ws + 117440512);               // [S][64]         524288 B
    float* aout = (float*)(ws + 117964800);               // [S][4096]     33554432 B
    unsigned char* mask = (unsigned char*)(ws + 151519232); // [S][S]       4194304 B
    // A-zone (dead before pack_*):
    float* qa   = (float*)(ws + 155713536);               // [S][1536]     12582912 B
    float* iq   = (float*)(ws + 168296448);               // [S][2048]     16777216 B
    float* ik   = (float*)(ws + 185073664);               // [S][128]       1048576 B
    float* iww  = (float*)(ws + 186122240);               // [S][16]         131072 B
    float* iscr = (float*)(ws + 186253312);               // [S][S]        16777216 B
    float* ckv  = (float*)(ws + 203030528);               // [S][576]       4718592 B
    float* kvn  = (float*)(ws + 207749120);               // [S][512]       4194304 B
    // overlays (only live after topk / pack):
    unsigned short* qb16 = (unsigned short*)(ws + 155713536);  // 25165824 B (over qa+iq)
    unsigned short* kb16 = (unsigned short*)(ws + 180879360);  // 25165824 B (over iq..kvn)
    unsigned short* vT   = (unsigned short*)(ws + 0);          // 16777216 B (over dead qbuf)
    (void)ws_size; (void)in_sizes; (void)n_in; (void)out_size;

    const dim3 blk(256);

    // q path
    gemm64<<<dim3(QRANK / 64, S_LEN / 64), blk, 0, stream>>>(hidden, q_a_w, qa, S_LEN, QRANK, HIDDEN);
    rmsnorm_kernel<<<S_LEN, blk, 0, stream>>>(qa, q_a_norm_w, qa, QRANK, QRANK);
    gemm64<<<dim3(NHEAD * D_QK / 64, S_LEN / 64), blk, 0, stream>>>(qa, q_b_w, qbuf, S_LEN, NHEAD * D_QK, QRANK);

    // kv path
    gemm64<<<dim3((KVRANK + D_ROPE + 63) / 64, S_LEN / 64), blk, 0, stream>>>(hidden, kv_a_w, ckv, S_LEN, KVRANK + D_ROPE, HIDDEN);
    rmsnorm_kernel<<<S_LEN, blk, 0, stream>>>(ckv, kv_a_norm_w, kvn, KVRANK, KVRANK + D_ROPE);
    gemm64<<<dim3(NHEAD * 256 / 64, S_LEN / 64), blk, 0, stream>>>(kvn, kv_b_w, kv, S_LEN, NHEAD * 256, KVRANK);

    // rope
    rope_q_kernel<<<(S_LEN * NHEAD * 32 + 255) / 256, blk, 0, stream>>>(qbuf);
    rope_k_kernel<<<(S_LEN * 32 + 255) / 256, blk, 0, stream>>>(ckv, kpe);

    // indexer
    gemm64<<<dim3(IDXH * IDXD / 64, S_LEN / 64), blk, 0, stream>>>(hidden, idx_wq_w, iq, S_LEN, IDXH * IDXD, HIDDEN);
    gemm64<<<dim3(IDXD / 64, S_LEN / 64), blk, 0, stream>>>(hidden, idx_wk_w, ik, S_LEN, IDXD, HIDDEN);
    gemm64<<<dim3(1, S_LEN / 64), blk, 0, stream>>>(hidden, idx_weights_w, iww, S_LEN, IDXH, HIDDEN);
    idx_score_kernel<<<dim3(S_LEN / 64, S_LEN / 64), blk, 0, stream>>>(iq, ik, iww, iscr);
    topk_kernel<<<S_LEN, blk, 0, stream>>>(iscr, mask);

    // attention prep (A-zone dead from here; qbuf dead after pack_q)
    pack_q_kernel<<<(S_LEN * NHEAD * D_QK) / 256, blk, 0, stream>>>(qbuf, qb16);
    pack_k_kernel<<<(S_LEN * NHEAD * D_QK) / 256, blk, 0, stream>>>(kv, kpe, kb16);
    pack_vT_kernel<<<dim3(S_LEN / 64, NHEAD), blk, 0, stream>>>(kv, vT);

    // attention
    attn_mfma_kernel<<<dim3(S_LEN / 64, NHEAD), blk, 0, stream>>>(qb16, kb16, vT, mask, aout);

    // output projection
    gemm64<<<dim3(HIDDEN / 64, S_LEN / 64), blk, 0, stream>>>(aout, o_w, out, S_LEN, HIDDEN, HIDDEN);
}

// Round 3
// 2454.186 us; speedup vs baseline: 11.2619x; 1.8341x over previous
//
#include <hip/hip_runtime.h>
#include <math.h>

#define S_LEN 2048
#define HIDDEN 4096
#define NHEAD 32
#define D_NOPE 128
#define D_ROPE 64
#define D_V 128
#define D_QK 192
#define QRANK 1536
#define KVRANK 512
#define IDXH 16
#define IDXD 128
#define KSEL 1024

typedef __attribute__((ext_vector_type(8))) short bf16x8;
typedef __attribute__((ext_vector_type(4))) float f32x4;
typedef __attribute__((ext_vector_type(4))) unsigned short u16x4;

__device__ __forceinline__ unsigned short f2b(float f) {
    union { float f; unsigned int u; } x; x.f = f;
    unsigned int r = x.u + 0x7FFFu + ((x.u >> 16) & 1u);
    return (unsigned short)(r >> 16);
}
__device__ __forceinline__ float b2f(unsigned short u) {
    union { unsigned int u; float f; } x; x.u = ((unsigned int)u) << 16; return x.f;
}

// global -> LDS direct load, 16B per lane. LDS dest = wave-uniform base + lane*16.
__device__ __forceinline__ void gload16(const void* g, const void* l) {
    __builtin_amdgcn_global_load_lds(
        (const __attribute__((address_space(1))) unsigned int*)(unsigned long long)g,
        (__attribute__((address_space(3))) unsigned int*)(unsigned int)(unsigned long long)l,
        16, 0, 0);
}

// ---------------------------------------------------------------------------
// bf16 MFMA GEMM: C[M,N] = alpha * A[M,K] @ Bt[N,K]^T. M,N multiples of 128,
// K multiple of 32. 128x128 tile, 4 waves, 16x16x32 MFMA, global_load_lds,
// XOR-swizzle via pre-swizzled global source (T21).
// ---------------------------------------------------------------------------
template <int OUT_BF16>
__global__ __launch_bounds__(256) void gemm_bf16(const unsigned short* __restrict__ A,
                                                 const unsigned short* __restrict__ Bt,
                                                 void* __restrict__ Cv,
                                                 int K, int ldc, float alpha) {
    __shared__ __align__(16) unsigned char lds[16384];  // As 8KB | Bs 8KB
    const int tid = threadIdx.x;
    const int w = tid >> 6, lane = tid & 63;
    const int lr = lane & 15, g = lane >> 4;
    const int bm = blockIdx.y * 128, bn = blockIdx.x * 128;
    const int wm = (w >> 1) * 64, wn = (w & 1) * 64;

    f32x4 acc[4][4];
#pragma unroll
    for (int i = 0; i < 4; ++i)
#pragma unroll
        for (int j = 0; j < 4; ++j) acc[i][j] = (f32x4){0.f, 0.f, 0.f, 0.f};

    // per-lane staging source offsets (elements), swizzled k-slot
    int a_off[2], b_off[2];
#pragma unroll
    for (int issue = 0; issue < 2; ++issue) {
        const int off = issue * 4096 + w * 1024 + lane * 16;
        const int row = off >> 6, slot = (off >> 4) & 3;
        a_off[issue] = (bm + row) * K + ((slot ^ (row & 3)) << 3);
        b_off[issue] = (bn + row) * K + ((slot ^ (row & 3)) << 3);
    }

    for (int k0 = 0; k0 < K; k0 += 32) {
        gload16(A + a_off[0] + k0, lds + w * 1024);
        gload16(A + a_off[1] + k0, lds + 4096 + w * 1024);
        gload16(Bt + b_off[0] + k0, lds + 8192 + w * 1024);
        gload16(Bt + b_off[1] + k0, lds + 8192 + 4096 + w * 1024);
        asm volatile("s_waitcnt vmcnt(0)" ::: "memory");
        __syncthreads();

        bf16x8 af[4], bfr[4];
#pragma unroll
        for (int i = 0; i < 4; ++i) {
            const int rowA = wm + i * 16 + lr;
            af[i] = *(const bf16x8*)(lds + rowA * 64 + ((g ^ (rowA & 3)) << 4));
            const int rowB = wn + i * 16 + lr;
            bfr[i] = *(const bf16x8*)(lds + 8192 + rowB * 64 + ((g ^ (rowB & 3)) << 4));
        }
#pragma unroll
        for (int i = 0; i < 4; ++i)
#pragma unroll
            for (int j = 0; j < 4; ++j)
                acc[i][j] = __builtin_amdgcn_mfma_f32_16x16x32_bf16(af[i], bfr[j], acc[i][j], 0, 0, 0);
        __syncthreads();
    }

#pragma unroll
    for (int i = 0; i < 4; ++i) {
        const int m = bm + wm + i * 16 + g * 4;
#pragma unroll
        for (int j = 0; j < 4; ++j) {
            const int n = bn + wn + j * 16 + lr;
            if (OUT_BF16) {
                unsigned short* Cb = (unsigned short*)Cv;
#pragma unroll
                for (int r = 0; r < 4; ++r)
                    Cb[(size_t)(m + r) * ldc + n] = f2b(acc[i][j][r] * alpha);
            } else {
                float* Cf = (float*)Cv;
#pragma unroll
                for (int r = 0; r < 4; ++r)
                    Cf[(size_t)(m + r) * ldc + n] = acc[i][j][r] * alpha;
            }
        }
    }
}

// ---------------------------------------------------------------------------
// fp32 -> bf16 elementwise (4/thread)
// ---------------------------------------------------------------------------
__global__ __launch_bounds__(256) void convb16(const float* __restrict__ src,
                                               unsigned short* __restrict__ dst, int n4) {
    const int i = blockIdx.x * 256 + threadIdx.x;
    if (i >= n4) return;
    const float4 v = ((const float4*)src)[i];
    u16x4 r = {f2b(v.x), f2b(v.y), f2b(v.z), f2b(v.w)};
    *(u16x4*)(dst + (size_t)i * 4) = r;
}

// ---------------------------------------------------------------------------
// Weight transpose-convert: Bt[n][k] = bf16(W[k][n]); rows n0+n >= Nsrc -> 0.
// grid (Ndst/64, K/64)
// ---------------------------------------------------------------------------
__global__ __launch_bounds__(256) void wtrans(const float* __restrict__ W,
                                              unsigned short* __restrict__ Bt,
                                              int K, int Nsrc) {
    const int n0 = blockIdx.x * 64, k0 = blockIdx.y * 64;
    __shared__ unsigned short lv[64][72];
    const int tid = threadIdx.x;
#pragma unroll
    for (int it = 0; it < 16; ++it) {
        const int idx = tid + it * 256;
        const int kr = idx >> 6, n = idx & 63;
        const float v = (n0 + n < Nsrc) ? W[(size_t)(k0 + kr) * Nsrc + n0 + n] : 0.f;
        lv[n][kr] = f2b(v);
    }
    __syncthreads();
#pragma unroll
    for (int it = 0; it < 16; ++it) {
        const int idx = tid + it * 256;
        const int n = idx >> 6, kk = idx & 63;
        Bt[(size_t)(n0 + n) * K + k0 + kk] = lv[n][kk];
    }
}

// ---------------------------------------------------------------------------
// fp32 GEMM (kept for the indexer path only — mask stability)
// ---------------------------------------------------------------------------
__global__ __launch_bounds__(256) void gemm64(const float* __restrict__ A,
                                              const float* __restrict__ B,
                                              float* __restrict__ C,
                                              int M, int N, int K) {
    __shared__ float As[16][68];
    __shared__ float Bs[16][68];
    const int tid = threadIdx.x;
    const int tx = tid & 15, ty = tid >> 4;
    const int bn = blockIdx.x * 64, bm = blockIdx.y * 64;

    float c[4][4] = {};

    const int ar = tid >> 2, ak = (tid & 3) << 2;
    const int bk = tid >> 4, bn4 = (tid & 15) << 2;

    for (int k0 = 0; k0 < K; k0 += 16) {
        {
            const float4 v = *(const float4*)(A + (size_t)(bm + ar) * K + k0 + ak);
            As[ak + 0][ar] = v.x;
            As[ak + 1][ar] = v.y;
            As[ak + 2][ar] = v.z;
            As[ak + 3][ar] = v.w;
        }
        {
            const float* bp = B + (size_t)(k0 + bk) * N + bn + bn4;
            if (bn + bn4 + 4 <= N) {
                *(float4*)&Bs[bk][bn4] = *(const float4*)bp;
            } else {
                for (int i = 0; i < 4; ++i)
                    Bs[bk][bn4 + i] = (bn + bn4 + i < N) ? bp[i] : 0.f;
            }
        }
        __syncthreads();
#pragma unroll
        for (int kk = 0; kk < 16; ++kk) {
            const float4 a4 = *(const float4*)&As[kk][ty * 4];
            const float4 b4 = *(const float4*)&Bs[kk][tx * 4];
            const float a[4] = {a4.x, a4.y, a4.z, a4.w};
            const float b[4] = {b4.x, b4.y, b4.z, b4.w};
#pragma unroll
            for (int i = 0; i < 4; ++i)
#pragma unroll
                for (int j = 0; j < 4; ++j) c[i][j] += a[i] * b[j];
        }
        __syncthreads();
    }
#pragma unroll
    for (int i = 0; i < 4; ++i) {
        const int m = bm + ty * 4 + i;
#pragma unroll
        for (int j = 0; j < 4; ++j) {
            const int n = bn + tx * 4 + j;
            if (n < N) C[(size_t)m * N + n] = c[i][j];
        }
    }
}

// ---------------------------------------------------------------------------
// RMSNorm fp32 in (strided) -> bf16 out
// ---------------------------------------------------------------------------
__global__ __launch_bounds__(256) void rmsnormb(const float* __restrict__ in,
                                                const float* __restrict__ w,
                                                unsigned short* __restrict__ out,
                                                int W, int in_stride) {
    const int row = blockIdx.x;
    const int tid = threadIdx.x;
    const float* x = in + (size_t)row * in_stride;
    float ss = 0.f;
    for (int i = tid; i < W; i += 256) {
        float v = x[i];
        ss += v * v;
    }
    __shared__ float red[256];
    red[tid] = ss;
    __syncthreads();
    for (int s = 128; s > 0; s >>= 1) {
        if (tid < s) red[tid] += red[tid + s];
        __syncthreads();
    }
    const float scale = rsqrtf(red[0] / (float)W + 1e-5f);
    for (int i = tid; i < W; i += 256) out[(size_t)row * W + i] = f2b(x[i] * scale * w[i]);
}

// ---------------------------------------------------------------------------
// RoPE on bf16 q (in-place, pre-scaled values; rotation commutes with scale)
// q layout [S][6144], pe at h*192+128.
// ---------------------------------------------------------------------------
__global__ __launch_bounds__(256) void rope_q16(unsigned short* __restrict__ q) {
    const int idx = blockIdx.x * 256 + threadIdx.x;
    if (idx >= S_LEN * NHEAD * (D_ROPE / 2)) return;
    const int i = idx & 31;
    const int h = (idx >> 5) & 31;
    const int s = idx >> 10;
    const float inv = __expf(-(float)i * (logf(10000.f) / 32.f));
    const float ang = (float)s * inv;
    const float cs = cosf(ang), sn = sinf(ang);
    unsigned short* p = q + (size_t)s * (NHEAD * D_QK) + h * D_QK + D_NOPE + 2 * i;
    const float x0 = b2f(p[0]), x1 = b2f(p[1]);
    p[0] = f2b(x0 * cs - x1 * sn);
    p[1] = f2b(x1 * cs + x0 * sn);
}

// RoPE k_pe: read C1[s][2048 + d] fp32 (stride 2176), write bf16 kpe16[S][64]
__global__ __launch_bounds__(256) void rope_k16(const float* __restrict__ C1,
                                                unsigned short* __restrict__ kpe16) {
    const int idx = blockIdx.x * 256 + threadIdx.x;
    if (idx >= S_LEN * (D_ROPE / 2)) return;
    const int i = idx & 31;
    const int s = idx >> 5;
    const float inv = __expf(-(float)i * (logf(10000.f) / 32.f));
    const float ang = (float)s * inv;
    const float cs = cosf(ang), sn = sinf(ang);
    const float* p = C1 + (size_t)s * 2176 + 2048 + 2 * i;
    const float x0 = p[0], x1 = p[1];
    kpe16[(size_t)s * D_ROPE + 2 * i] = f2b(x0 * cs - x1 * sn);
    kpe16[(size_t)s * D_ROPE + 2 * i + 1] = f2b(x1 * cs + x0 * sn);
}

// ---------------------------------------------------------------------------
// Indexer scores (fp32, unchanged)
// ---------------------------------------------------------------------------
__global__ __launch_bounds__(256) void idx_score_kernel(const float* __restrict__ iq,
                                                        const float* __restrict__ ik,
                                                        const float* __restrict__ iw,
                                                        float* __restrict__ iscore) {
    const int kt = blockIdx.x, qt = blockIdx.y;
    if (kt > qt) return;
    const int q0 = qt * 64, k0 = kt * 64;
    __shared__ float iks[64][129];
    __shared__ float iqs[64][129];
    __shared__ float iws[64][16];
    const int tid = threadIdx.x;
    const int tx = tid & 15, ty = tid >> 4;

    for (int idx = tid; idx < 64 * 32; idx += 256) {
        const int r = idx >> 5, c4 = (idx & 31) << 2;
        const float4 v = *(const float4*)(ik + (size_t)(k0 + r) * IDXD + c4);
        iks[r][c4] = v.x; iks[r][c4 + 1] = v.y; iks[r][c4 + 2] = v.z; iks[r][c4 + 3] = v.w;
    }
    for (int idx = tid; idx < 64 * 16; idx += 256) {
        const int r = idx >> 4, c = idx & 15;
        iws[r][c] = iw[(size_t)(q0 + r) * IDXH + c] * 0.25f;
    }

    float acc[4][4] = {};
    for (int n = 0; n < IDXH; ++n) {
        __syncthreads();
        for (int idx = tid; idx < 64 * 32; idx += 256) {
            const int r = idx >> 5, c4 = (idx & 31) << 2;
            const float4 v = *(const float4*)(iq + (size_t)(q0 + r) * (IDXH * IDXD) + n * IDXD + c4);
            iqs[r][c4] = v.x; iqs[r][c4 + 1] = v.y; iqs[r][c4 + 2] = v.z; iqs[r][c4 + 3] = v.w;
        }
        __syncthreads();
        float dot[4][4] = {};
        for (int d = 0; d < IDXD; ++d) {
            float a[4], b[4];
#pragma unroll
            for (int i = 0; i < 4; ++i) a[i] = iqs[ty * 4 + i][d];
#pragma unroll
            for (int j = 0; j < 4; ++j) b[j] = iks[tx * 4 + j][d];
#pragma unroll
            for (int i = 0; i < 4; ++i)
#pragma unroll
                for (int j = 0; j < 4; ++j) dot[i][j] += a[i] * b[j];
        }
#pragma unroll
        for (int i = 0; i < 4; ++i) {
            const float w = iws[ty * 4 + i][n];
#pragma unroll
            for (int j = 0; j < 4; ++j) acc[i][j] += w * fmaxf(dot[i][j], 0.f);
        }
    }
    const float sc = 0.08838834764831845f;
#pragma unroll
    for (int i = 0; i < 4; ++i)
#pragma unroll
        for (int j = 0; j < 4; ++j) {
            const int qq = q0 + ty * 4 + i, kk = k0 + tx * 4 + j;
            iscore[(size_t)qq * S_LEN + kk] = acc[i][j] * sc;
        }
}

// ---------------------------------------------------------------------------
// Exact top-K per row (unchanged)
// ---------------------------------------------------------------------------
__global__ __launch_bounds__(256) void topk_kernel(const float* __restrict__ iscore,
                                                   unsigned char* __restrict__ mask) {
    const int q = blockIdx.x;
    const int tid = threadIdx.x;
    const int nk = q + 1;
    unsigned char* mrow = mask + (size_t)q * S_LEN;
    if (nk <= KSEL) {
        for (int k = tid; k < S_LEN; k += 256) mrow[k] = (k <= q) ? 1 : 0;
        return;
    }
    __shared__ unsigned int uv[S_LEN];
    const float* srow = iscore + (size_t)q * S_LEN;
    for (int k = tid; k < nk; k += 256) {
        unsigned int b = __float_as_uint(srow[k]);
        uv[k] = (b & 0x80000000u) ? ~b : (b | 0x80000000u);
    }
    __syncthreads();
    __shared__ int cnt;
    unsigned int lo = 0u, hi = 0xFFFFFFFFu;
    while (lo < hi) {
        const unsigned long long range = (unsigned long long)(hi - lo);
        const unsigned int mid = lo + (unsigned int)((range + 1ull) >> 1);
        if (tid == 0) cnt = 0;
        __syncthreads();
        int c = 0;
        for (int k = tid; k < nk; k += 256) c += (uv[k] >= mid) ? 1 : 0;
        atomicAdd(&cnt, c);
        __syncthreads();
        const int total = cnt;
        __syncthreads();
        if (total >= KSEL) lo = mid; else hi = mid - 1;
    }
    const unsigned int T = lo;
    if (tid == 0) cnt = 0;
    __syncthreads();
    {
        int c = 0;
        for (int k = tid; k < nk; k += 256) c += (uv[k] > T) ? 1 : 0;
        atomicAdd(&cnt, c);
    }
    __syncthreads();
    const int r = KSEL - cnt;
    for (int k = tid; k < S_LEN; k += 256) {
        unsigned char mv = 0;
        if (k < nk) {
            const unsigned int u = uv[k];
            if (u > T) {
                mv = 1;
            } else if (u == T) {
                int rank = 0;
                for (int j = 0; j < k; ++j) rank += (uv[j] == T) ? 1 : 0;
                mv = (rank < r) ? 1 : 0;
            }
        }
        mrow[k] = mv;
    }
}

// ---------------------------------------------------------------------------
// kb16[h][s][192] = {kv16[s][h*256+d] (d<128), kpe16[s][d-128]}
// ---------------------------------------------------------------------------
__global__ __launch_bounds__(256) void pack_k16(const unsigned short* __restrict__ kv16,
                                                const unsigned short* __restrict__ kpe16,
                                                unsigned short* __restrict__ kb16) {
    const int idx = blockIdx.x * 256 + threadIdx.x;
    const int h = idx / (S_LEN * D_QK);
    const int rem = idx - h * (S_LEN * D_QK);
    const int s = rem / D_QK;
    const int d = rem - s * D_QK;
    kb16[idx] = (d < 128) ? kv16[(size_t)s * 8192 + h * 256 + d]
                          : kpe16[(size_t)s * D_ROPE + (d - 128)];
}

// vT[h][d][s] = kv16[s][h*256+128+d] (bf16 transpose)
__global__ __launch_bounds__(256) void pack_vT16(const unsigned short* __restrict__ kv16,
                                                 unsigned short* __restrict__ vT) {
    const int st = blockIdx.x, h = blockIdx.y;
    const int s0 = st * 64;
    __shared__ unsigned short lv[64][130];
    const int tid = threadIdx.x;
#pragma unroll
    for (int it = 0; it < 32; ++it) {
        const int idx = tid + it * 256;
        const int sl = idx >> 7, d = idx & 127;
        lv[sl][d] = kv16[(size_t)(s0 + sl) * 8192 + h * 256 + 128 + d];
    }
    __syncthreads();
#pragma unroll
    for (int it = 0; it < 32; ++it) {
        const int idx = tid + it * 256;
        const int d = idx >> 6, sl = idx & 63;
        vT[(size_t)(h * 128 + d) * S_LEN + s0 + sl] = lv[sl][d];
    }
}

// ---------------------------------------------------------------------------
// MFMA flash attention. Q read directly from qbuf16 [S][6144] (pre-scaled,
// rope'd). Output bf16 ab16 [S][4096]. K/V/mask staging as round 2.
// ---------------------------------------------------------------------------
#define ALD_K 0
#define ALD_V 12288
#define ALD_P 22528
#define ALD_M 27648

__global__ __launch_bounds__(256) void attn_mfma_kernel(
    const unsigned short* __restrict__ qbuf16,
    const unsigned short* __restrict__ kb16,
    const unsigned short* __restrict__ vT,
    const unsigned char* __restrict__ mask,
    unsigned short* __restrict__ ab16) {
    __shared__ __align__(16) unsigned char smem[29696];
    const int qt = blockIdx.x, h = blockIdx.y;
    const int q0 = qt * 64;
    const int tid = threadIdx.x;
    const int w = tid >> 6, lane = tid & 63;
    const int g = lane >> 4, lr = lane & 15;

    bf16x8 qf[6];
    {
        const unsigned short* qrow = qbuf16 + (size_t)(q0 + w * 16 + lr) * (NHEAD * D_QK) + h * D_QK;
#pragma unroll
        for (int c = 0; c < 6; ++c) qf[c] = *(const bf16x8*)(qrow + c * 32 + g * 8);
    }

    f32x4 O[8];
#pragma unroll
    for (int db = 0; db < 8; ++db) O[db] = (f32x4){0.f, 0.f, 0.f, 0.f};
    float mS[4] = {-INFINITY, -INFINITY, -INFINITY, -INFINITY};
    float lS[4] = {0.f, 0.f, 0.f, 0.f};

    const int nt = (q0 + 64) >> 5;
    const unsigned char* kbase = (const unsigned char*)(kb16 + (size_t)h * S_LEN * D_QK);
    const unsigned char* vbase = (const unsigned char*)(vT + (size_t)h * 128 * S_LEN);
    const unsigned char* mbase = mask + (size_t)q0 * S_LEN;
    unsigned short* Pb = (unsigned short*)(smem + ALD_P + w * 1280);

    for (int t = 0; t < nt; ++t) {
        const int k0 = t << 5;
#pragma unroll
        for (int it = 0; it < 3; ++it) {
            const int j = tid + it * 256;
            const int row = j / 24, cs = j - row * 24;
            const int colb = cs << 4;
            const uint4 v = *(const uint4*)(kbase + (size_t)(k0 + row) * 384 + colb);
            *(uint4*)(smem + ALD_K + row * 384 + (colb ^ ((row & 7) << 4))) = v;
        }
#pragma unroll
        for (int it = 0; it < 2; ++it) {
            const int j = tid + it * 256;
            const int d = j >> 2, slot = j & 3;
            const uint4 v = *(const uint4*)(vbase + ((size_t)d * S_LEN + k0) * 2 + slot * 16);
            *(uint4*)(smem + ALD_V + d * 80 + slot * 16) = v;
        }
        {
            const int qr = tid >> 2, kc = (tid & 3) << 3;
            const uint2 v = *(const uint2*)(mbase + (size_t)qr * S_LEN + k0 + kc);
            *(uint2*)(smem + ALD_M + qr * 32 + kc) = v;
        }
        __syncthreads();

        f32x4 a0 = (f32x4){0.f, 0.f, 0.f, 0.f};
        f32x4 a1 = (f32x4){0.f, 0.f, 0.f, 0.f};
#pragma unroll
        for (int c = 0; c < 6; ++c) {
            const int colb = c * 64 + g * 16;
            const bf16x8 b0 = *(const bf16x8*)(smem + ALD_K + lr * 384 + (colb ^ ((lr & 7) << 4)));
            const bf16x8 b1 = *(const bf16x8*)(smem + ALD_K + (16 + lr) * 384 + (colb ^ ((lr & 7) << 4)));
            a0 = __builtin_amdgcn_mfma_f32_16x16x32_bf16(qf[c], b0, a0, 0, 0, 0);
            a1 = __builtin_amdgcn_mfma_f32_16x16x32_bf16(qf[c], b1, a1, 0, 0, 0);
        }

        float corr[4];
#pragma unroll
        for (int r = 0; r < 4; ++r) {
            const int qrl = w * 16 + g * 4 + r;
            const float s0 = smem[ALD_M + qrl * 32 + lr] ? a0[r] : -INFINITY;
            const float s1 = smem[ALD_M + qrl * 32 + 16 + lr] ? a1[r] : -INFINITY;
            float tm = fmaxf(s0, s1);
            tm = fmaxf(tm, __shfl_xor(tm, 1));
            tm = fmaxf(tm, __shfl_xor(tm, 2));
            tm = fmaxf(tm, __shfl_xor(tm, 4));
            tm = fmaxf(tm, __shfl_xor(tm, 8));
            const float mn = fmaxf(mS[r], tm);
            const float co = (mS[r] > -INFINITY) ? __expf(mS[r] - mn) : 0.f;
            const float p0 = (s0 > -INFINITY) ? __expf(s0 - mn) : 0.f;
            const float p1 = (s1 > -INFINITY) ? __expf(s1 - mn) : 0.f;
            float rs = p0 + p1;
            rs += __shfl_xor(rs, 1);
            rs += __shfl_xor(rs, 2);
            rs += __shfl_xor(rs, 4);
            rs += __shfl_xor(rs, 8);
            lS[r] = lS[r] * co + rs;
            mS[r] = mn;
            corr[r] = co;
            Pb[(g * 4 + r) * 40 + lr] = f2b(p0);
            Pb[(g * 4 + r) * 40 + 16 + lr] = f2b(p1);
        }
#pragma unroll
        for (int db = 0; db < 8; ++db) {
            O[db][0] *= corr[0];
            O[db][1] *= corr[1];
            O[db][2] *= corr[2];
            O[db][3] *= corr[3];
        }

        asm volatile("s_waitcnt lgkmcnt(0)" ::: "memory");
        __builtin_amdgcn_sched_barrier(0);

        const bf16x8 pA = *(const bf16x8*)((const unsigned char*)Pb + lr * 80 + g * 16);
#pragma unroll
        for (int db = 0; db < 8; ++db) {
            const bf16x8 bV = *(const bf16x8*)(smem + ALD_V + (db * 16 + lr) * 80 + g * 16);
            O[db] = __builtin_amdgcn_mfma_f32_16x16x32_bf16(pA, bV, O[db], 0, 0, 0);
        }
        __syncthreads();
    }

#pragma unroll
    for (int r = 0; r < 4; ++r) {
        const float inv = (lS[r] > 0.f) ? 1.f / lS[r] : 0.f;
        const int qg = q0 + w * 16 + g * 4 + r;
        unsigned short* orow = ab16 + (size_t)qg * (NHEAD * D_V) + h * D_V;
#pragma unroll
        for (int db = 0; db < 8; ++db) orow[db * 16 + lr] = f2b(O[db][r] * inv);
    }
}

// ---------------------------------------------------------------------------
extern "C" void kernel_launch(void* const* d_in, const int* in_sizes, int n_in,
                              void* d_out, int out_size, void* d_ws, size_t ws_size,
                              hipStream_t stream) {
    const float* hidden        = (const float*)d_in[0];
    const float* q_a_w         = (const float*)d_in[1];
    const float* q_a_norm_w    = (const float*)d_in[2];
    const float* q_b_w         = (const float*)d_in[3];
    const float* kv_a_w        = (const float*)d_in[4];
    const float* kv_a_norm_w   = (const float*)d_in[5];
    const float* kv_b_w        = (const float*)d_in[6];
    const float* o_w           = (const float*)d_in[7];
    const float* idx_wq_w      = (const float*)d_in[8];
    const float* idx_wk_w      = (const float*)d_in[9];
    const float* idx_weights_w = (const float*)d_in[10];
    float* out = (float*)d_out;

    char* ws = (char*)d_ws;
    // Z0: BtAll(17.8M) -> kv16(33.6M) -> owT(33.6M)
    unsigned short* BtAll = (unsigned short*)(ws + 0);
    unsigned short* kv16  = (unsigned short*)(ws + 0);
    unsigned short* owT   = (unsigned short*)(ws + 0);
    // Z1: h16(16.8M) -> qbuf16(25.2M)
    unsigned short* h16    = (unsigned short*)(ws + 33554432);
    unsigned short* qbuf16 = (unsigned short*)(ws + 33554432);
    // Z2: C1 fp32 [2048][2176] (17.8M) -> vT(16.8M)
    float* C1          = (float*)(ws + 58720256);
    unsigned short* vT = (unsigned short*)(ws + 58720256);
    // Z3: iq(16.8M) -> ab16(16.8M)
    float* iq            = (float*)(ws + 76546048);
    unsigned short* ab16 = (unsigned short*)(ws + 76546048);
    // Z4: ik, iww
    float* ik  = (float*)(ws + 93323264);
    float* iww = (float*)(ws + 94371840);
    // Z5: iscr(16.8M) -> kb16(25.2M)
    float* iscr          = (float*)(ws + 94502912);
    unsigned short* kb16 = (unsigned short*)(ws + 94502912);
    // Z6..: mask, qa16, kvn16, kpe16, qbT, kvbT
    unsigned char* mask   = (unsigned char*)(ws + 119668736);
    unsigned short* qa16  = (unsigned short*)(ws + 123863040);
    unsigned short* kvn16 = (unsigned short*)(ws + 130154496);
    unsigned short* kpe16 = (unsigned short*)(ws + 132251648);
    unsigned short* qbT   = (unsigned short*)(ws + 132513792);
    unsigned short* kvbT  = (unsigned short*)(ws + 151388160);
    (void)ws_size; (void)in_sizes; (void)n_in; (void)out_size;

    const dim3 blk(256);
    const float QK_SCALE = 0.07216878364870323f;  // 1/sqrt(192)

    // converts + stage-1 fused weights (q_a | kv_a | zero pad) -> [2176][4096]
    convb16<<<8192, blk, 0, stream>>>(hidden, h16, (S_LEN * HIDDEN) / 4);
    wtrans<<<dim3(24, 64), blk, 0, stream>>>(q_a_w, BtAll, HIDDEN, QRANK);
    wtrans<<<dim3(9, 64), blk, 0, stream>>>(kv_a_w, BtAll + (size_t)1536 * HIDDEN, HIDDEN, KVRANK + D_ROPE);
    wtrans<<<dim3(1, 64), blk, 0, stream>>>(q_a_w, BtAll + (size_t)2112 * HIDDEN, HIDDEN, 0);  // zeros

    // stage-1: C1[2048][2176] = h16 @ BtAll^T
    gemm_bf16<0><<<dim3(17, 16), blk, 0, stream>>>(h16, BtAll, C1, HIDDEN, 2176, 1.f);

    rmsnormb<<<S_LEN, blk, 0, stream>>>(C1, q_a_norm_w, qa16, QRANK, 2176);
    rmsnormb<<<S_LEN, blk, 0, stream>>>(C1 + 1536, kv_a_norm_w, kvn16, KVRANK, 2176);
    rope_k16<<<(S_LEN * 32 + 255) / 256, blk, 0, stream>>>(C1, kpe16);

    // stage-2 weights + gemms
    wtrans<<<dim3(96, 24), blk, 0, stream>>>(q_b_w, qbT, QRANK, NHEAD * D_QK);
    wtrans<<<dim3(128, 8), blk, 0, stream>>>(kv_b_w, kvbT, KVRANK, NHEAD * 256);
    gemm_bf16<1><<<dim3(48, 16), blk, 0, stream>>>(qa16, qbT, qbuf16, QRANK, NHEAD * D_QK, QK_SCALE);
    gemm_bf16<1><<<dim3(64, 16), blk, 0, stream>>>(kvn16, kvbT, kv16, KVRANK, NHEAD * 256, 1.f);
    rope_q16<<<(S_LEN * NHEAD * 32 + 255) / 256, blk, 0, stream>>>(qbuf16);

    // indexer (fp32 — keeps top-k mask bit-stable vs reference)
    gemm64<<<dim3(32, 32), blk, 0, stream>>>(hidden, idx_wq_w, iq, S_LEN, IDXH * IDXD, HIDDEN);
    gemm64<<<dim3(2, 32), blk, 0, stream>>>(hidden, idx_wk_w, ik, S_LEN, IDXD, HIDDEN);
    gemm64<<<dim3(1, 32), blk, 0, stream>>>(hidden, idx_weights_w, iww, S_LEN, IDXH, HIDDEN);
    idx_score_kernel<<<dim3(32, 32), blk, 0, stream>>>(iq, ik, iww, iscr);
    topk_kernel<<<S_LEN, blk, 0, stream>>>(iscr, mask);

    // attention prep + attention
    pack_k16<<<(NHEAD * S_LEN * D_QK) / 256, blk, 0, stream>>>(kv16, kpe16, kb16);
    pack_vT16<<<dim3(S_LEN / 64, NHEAD), blk, 0, stream>>>(kv16, vT);
    attn_mfma_kernel<<<dim3(S_LEN / 64, NHEAD), blk, 0, stream>>>(qbuf16, kb16, vT, mask, ab16);

    // output projection (after kv16 dead -> owT overlays Z0)
    wtrans<<<dim3(64, 64), blk, 0, stream>>>(o_w, owT, NHEAD * D_V, HIDDEN);
    gemm_bf16<0><<<dim3(32, 16), blk, 0, stream>>>(ab16, owT, out, NHEAD * D_V, HIDDEN, 1.f);
}

// Round 4
// 1297.621 us; speedup vs baseline: 21.2996x; 1.8913x over previous
//
#include <hip/hip_runtime.h>
#include <math.h>

#define S_LEN 2048
#define HIDDEN 4096
#define NHEAD 32
#define D_NOPE 128
#define D_ROPE 64
#define D_V 128
#define D_QK 192
#define QRANK 1536
#define KVRANK 512
#define IDXH 16
#define IDXD 128
#define KSEL 1024
#define NIDX 2304  // 2048 (wq) + 128 (wk) + 16 (weights) + 112 pad

typedef __attribute__((ext_vector_type(8))) short bf16x8;
typedef __attribute__((ext_vector_type(4))) float f32x4;
typedef __attribute__((ext_vector_type(4))) unsigned short u16x4;

__device__ __forceinline__ unsigned short f2b(float f) {
    union { float f; unsigned int u; } x; x.f = f;
    unsigned int r = x.u + 0x7FFFu + ((x.u >> 16) & 1u);
    return (unsigned short)(r >> 16);
}
__device__ __forceinline__ float b2f(unsigned short u) {
    union { unsigned int u; float f; } x; x.u = ((unsigned int)u) << 16; return x.f;
}

// global -> LDS direct load, 16B per lane. LDS dest = wave-uniform base + lane*16.
__device__ __forceinline__ void gload16(const void* g, const void* l) {
    __builtin_amdgcn_global_load_lds(
        (const __attribute__((address_space(1))) unsigned int*)(unsigned long long)g,
        (__attribute__((address_space(3))) unsigned int*)(unsigned int)(unsigned long long)l,
        16, 0, 0);
}

// ---------------------------------------------------------------------------
// bf16 MFMA GEMM: C[M,N] = alpha * A[M,K] @ Bt[N,K]^T. 128x128 tile.
// ---------------------------------------------------------------------------
template <int OUT_BF16>
__global__ __launch_bounds__(256) void gemm_bf16(const unsigned short* __restrict__ A,
                                                 const unsigned short* __restrict__ Bt,
                                                 void* __restrict__ Cv,
                                                 int K, int ldc, float alpha) {
    __shared__ __align__(16) unsigned char lds[16384];
    const int tid = threadIdx.x;
    const int w = tid >> 6, lane = tid & 63;
    const int lr = lane & 15, g = lane >> 4;
    const int bm = blockIdx.y * 128, bn = blockIdx.x * 128;
    const int wm = (w >> 1) * 64, wn = (w & 1) * 64;

    f32x4 acc[4][4];
#pragma unroll
    for (int i = 0; i < 4; ++i)
#pragma unroll
        for (int j = 0; j < 4; ++j) acc[i][j] = (f32x4){0.f, 0.f, 0.f, 0.f};

    int a_off[2], b_off[2];
#pragma unroll
    for (int issue = 0; issue < 2; ++issue) {
        const int off = issue * 4096 + w * 1024 + lane * 16;
        const int row = off >> 6, slot = (off >> 4) & 3;
        a_off[issue] = (bm + row) * K + ((slot ^ (row & 3)) << 3);
        b_off[issue] = (bn + row) * K + ((slot ^ (row & 3)) << 3);
    }

    for (int k0 = 0; k0 < K; k0 += 32) {
        gload16(A + a_off[0] + k0, lds + w * 1024);
        gload16(A + a_off[1] + k0, lds + 4096 + w * 1024);
        gload16(Bt + b_off[0] + k0, lds + 8192 + w * 1024);
        gload16(Bt + b_off[1] + k0, lds + 8192 + 4096 + w * 1024);
        asm volatile("s_waitcnt vmcnt(0)" ::: "memory");
        __syncthreads();

        bf16x8 af[4], bfr[4];
#pragma unroll
        for (int i = 0; i < 4; ++i) {
            const int rowA = wm + i * 16 + lr;
            af[i] = *(const bf16x8*)(lds + rowA * 64 + ((g ^ (rowA & 3)) << 4));
            const int rowB = wn + i * 16 + lr;
            bfr[i] = *(const bf16x8*)(lds + 8192 + rowB * 64 + ((g ^ (rowB & 3)) << 4));
        }
#pragma unroll
        for (int i = 0; i < 4; ++i)
#pragma unroll
            for (int j = 0; j < 4; ++j)
                acc[i][j] = __builtin_amdgcn_mfma_f32_16x16x32_bf16(af[i], bfr[j], acc[i][j], 0, 0, 0);
        __syncthreads();
    }

#pragma unroll
    for (int i = 0; i < 4; ++i) {
        const int m = bm + wm + i * 16 + g * 4;
#pragma unroll
        for (int j = 0; j < 4; ++j) {
            const int n = bn + wn + j * 16 + lr;
            if (OUT_BF16) {
                unsigned short* Cb = (unsigned short*)Cv;
#pragma unroll
                for (int r = 0; r < 4; ++r)
                    Cb[(size_t)(m + r) * ldc + n] = f2b(acc[i][j][r] * alpha);
            } else {
                float* Cf = (float*)Cv;
#pragma unroll
                for (int r = 0; r < 4; ++r)
                    Cf[(size_t)(m + r) * ldc + n] = acc[i][j][r] * alpha;
            }
        }
    }
}

// ---------------------------------------------------------------------------
// Split-precision (hi/lo bf16) MFMA GEMM: C = (Ah+Al) @ (Bh+Bl)^T, dropping
// the Al*Bl term. fp32 output. 128x128 tile, BK=32, 3 MFMA per fragment pair.
// ---------------------------------------------------------------------------
__global__ __launch_bounds__(256) void gemm_split(const unsigned short* __restrict__ Ah,
                                                  const unsigned short* __restrict__ Al,
                                                  const unsigned short* __restrict__ Bh,
                                                  const unsigned short* __restrict__ Bl,
                                                  float* __restrict__ C, int K, int ldc) {
    __shared__ __align__(16) unsigned char lds[32768];  // Ah|Al|Bh|Bl 8KB each
    const int tid = threadIdx.x;
    const int w = tid >> 6, lane = tid & 63;
    const int lr = lane & 15, g = lane >> 4;
    const int bm = blockIdx.y * 128, bn = blockIdx.x * 128;
    const int wm = (w >> 1) * 64, wn = (w & 1) * 64;

    f32x4 acc[4][4];
#pragma unroll
    for (int i = 0; i < 4; ++i)
#pragma unroll
        for (int j = 0; j < 4; ++j) acc[i][j] = (f32x4){0.f, 0.f, 0.f, 0.f};

    int a_off[2], b_off[2];
#pragma unroll
    for (int issue = 0; issue < 2; ++issue) {
        const int off = issue * 4096 + w * 1024 + lane * 16;
        const int row = off >> 6, slot = (off >> 4) & 3;
        a_off[issue] = (bm + row) * K + ((slot ^ (row & 3)) << 3);
        b_off[issue] = (bn + row) * K + ((slot ^ (row & 3)) << 3);
    }

    for (int k0 = 0; k0 < K; k0 += 32) {
        gload16(Ah + a_off[0] + k0, lds + w * 1024);
        gload16(Ah + a_off[1] + k0, lds + 4096 + w * 1024);
        gload16(Al + a_off[0] + k0, lds + 8192 + w * 1024);
        gload16(Al + a_off[1] + k0, lds + 8192 + 4096 + w * 1024);
        gload16(Bh + b_off[0] + k0, lds + 16384 + w * 1024);
        gload16(Bh + b_off[1] + k0, lds + 16384 + 4096 + w * 1024);
        gload16(Bl + b_off[0] + k0, lds + 24576 + w * 1024);
        gload16(Bl + b_off[1] + k0, lds + 24576 + 4096 + w * 1024);
        asm volatile("s_waitcnt vmcnt(0)" ::: "memory");
        __syncthreads();

        bf16x8 afh[4], afl[4], bfh[4], bfl[4];
#pragma unroll
        for (int i = 0; i < 4; ++i) {
            const int rowA = wm + i * 16 + lr;
            const int offA = rowA * 64 + ((g ^ (rowA & 3)) << 4);
            afh[i] = *(const bf16x8*)(lds + offA);
            afl[i] = *(const bf16x8*)(lds + 8192 + offA);
            const int rowB = wn + i * 16 + lr;
            const int offB = rowB * 64 + ((g ^ (rowB & 3)) << 4);
            bfh[i] = *(const bf16x8*)(lds + 16384 + offB);
            bfl[i] = *(const bf16x8*)(lds + 24576 + offB);
        }
#pragma unroll
        for (int i = 0; i < 4; ++i)
#pragma unroll
            for (int j = 0; j < 4; ++j) {
                acc[i][j] = __builtin_amdgcn_mfma_f32_16x16x32_bf16(afh[i], bfh[j], acc[i][j], 0, 0, 0);
                acc[i][j] = __builtin_amdgcn_mfma_f32_16x16x32_bf16(afh[i], bfl[j], acc[i][j], 0, 0, 0);
                acc[i][j] = __builtin_amdgcn_mfma_f32_16x16x32_bf16(afl[i], bfh[j], acc[i][j], 0, 0, 0);
            }
        __syncthreads();
    }

#pragma unroll
    for (int i = 0; i < 4; ++i) {
        const int m = bm + wm + i * 16 + g * 4;
#pragma unroll
        for (int j = 0; j < 4; ++j) {
            const int n = bn + wn + j * 16 + lr;
#pragma unroll
            for (int r = 0; r < 4; ++r)
                C[(size_t)(m + r) * ldc + n] = acc[i][j][r];
        }
    }
}

// ---------------------------------------------------------------------------
// fp32 -> (hi, lo) bf16 pair, 4 elems/thread
// ---------------------------------------------------------------------------
__global__ __launch_bounds__(256) void conv_split_h(const float* __restrict__ src,
                                                    unsigned short* __restrict__ dhi,
                                                    unsigned short* __restrict__ dlo) {
    const int i = blockIdx.x * 256 + threadIdx.x;
    const float4 v = ((const float4*)src)[i];
    u16x4 hi, lo;
    const float xs[4] = {v.x, v.y, v.z, v.w};
#pragma unroll
    for (int j = 0; j < 4; ++j) {
        const unsigned short h = f2b(xs[j]);
        hi[j] = h;
        lo[j] = f2b(xs[j] - b2f(h));
    }
    *(u16x4*)(dhi + (size_t)i * 4) = hi;
    *(u16x4*)(dlo + (size_t)i * 4) = lo;
}

// Cidx [2048][2304] fp32 -> iq hi/lo [2048][2048], ik hi/lo [2048][128]
__global__ __launch_bounds__(256) void conv_split_iq(const float* __restrict__ Cidx,
                                                     unsigned short* __restrict__ iqh,
                                                     unsigned short* __restrict__ iql,
                                                     unsigned short* __restrict__ ikh,
                                                     unsigned short* __restrict__ ikl) {
    const int i = blockIdx.x * 256 + threadIdx.x;  // over 2048*2176/4
    const int row = i / 544, c4 = (i - row * 544) * 4;
    const float4 v = *(const float4*)(Cidx + (size_t)row * NIDX + c4);
    u16x4 hi, lo;
    const float xs[4] = {v.x, v.y, v.z, v.w};
#pragma unroll
    for (int j = 0; j < 4; ++j) {
        const unsigned short h = f2b(xs[j]);
        hi[j] = h;
        lo[j] = f2b(xs[j] - b2f(h));
    }
    if (c4 < 2048) {
        *(u16x4*)(iqh + (size_t)row * 2048 + c4) = hi;
        *(u16x4*)(iql + (size_t)row * 2048 + c4) = lo;
    } else {
        *(u16x4*)(ikh + (size_t)row * 128 + c4 - 2048) = hi;
        *(u16x4*)(ikl + (size_t)row * 128 + c4 - 2048) = lo;
    }
}

// ---------------------------------------------------------------------------
// Weight transpose-convert: Bt[n][k] = bf16(W[k][n]); n >= Nsrc -> 0.
// ---------------------------------------------------------------------------
__global__ __launch_bounds__(256) void wtrans(const float* __restrict__ W,
                                              unsigned short* __restrict__ Bt,
                                              int K, int Nsrc) {
    const int n0 = blockIdx.x * 64, k0 = blockIdx.y * 64;
    __shared__ unsigned short lv[64][72];
    const int tid = threadIdx.x;
#pragma unroll
    for (int it = 0; it < 16; ++it) {
        const int idx = tid + it * 256;
        const int kr = idx >> 6, n = idx & 63;
        const float v = (n0 + n < Nsrc) ? W[(size_t)(k0 + kr) * Nsrc + n0 + n] : 0.f;
        lv[n][kr] = f2b(v);
    }
    __syncthreads();
#pragma unroll
    for (int it = 0; it < 16; ++it) {
        const int idx = tid + it * 256;
        const int n = idx >> 6, kk = idx & 63;
        Bt[(size_t)(n0 + n) * K + k0 + kk] = lv[n][kk];
    }
}

// split variant: writes hi and lo transposed weights
__global__ __launch_bounds__(256) void wtrans_split(const float* __restrict__ W,
                                                    unsigned short* __restrict__ Bth,
                                                    unsigned short* __restrict__ Btl,
                                                    int K, int Nsrc) {
    const int n0 = blockIdx.x * 64, k0 = blockIdx.y * 64;
    __shared__ float lv[64][65];
    const int tid = threadIdx.x;
#pragma unroll
    for (int it = 0; it < 16; ++it) {
        const int idx = tid + it * 256;
        const int kr = idx >> 6, n = idx & 63;
        lv[n][kr] = (n0 + n < Nsrc) ? W[(size_t)(k0 + kr) * Nsrc + n0 + n] : 0.f;
    }
    __syncthreads();
#pragma unroll
    for (int it = 0; it < 16; ++it) {
        const int idx = tid + it * 256;
        const int n = idx >> 6, kk = idx & 63;
        const float x = lv[n][kk];
        const unsigned short h = f2b(x);
        Bth[(size_t)(n0 + n) * K + k0 + kk] = h;
        Btl[(size_t)(n0 + n) * K + k0 + kk] = f2b(x - b2f(h));
    }
}

// ---------------------------------------------------------------------------
// RMSNorm fp32 in (strided) -> bf16 out
// ---------------------------------------------------------------------------
__global__ __launch_bounds__(256) void rmsnormb(const float* __restrict__ in,
                                                const float* __restrict__ w,
                                                unsigned short* __restrict__ out,
                                                int W, int in_stride) {
    const int row = blockIdx.x;
    const int tid = threadIdx.x;
    const float* x = in + (size_t)row * in_stride;
    float ss = 0.f;
    for (int i = tid; i < W; i += 256) {
        float v = x[i];
        ss += v * v;
    }
    __shared__ float red[256];
    red[tid] = ss;
    __syncthreads();
    for (int s = 128; s > 0; s >>= 1) {
        if (tid < s) red[tid] += red[tid + s];
        __syncthreads();
    }
    const float scale = rsqrtf(red[0] / (float)W + 1e-5f);
    for (int i = tid; i < W; i += 256) out[(size_t)row * W + i] = f2b(x[i] * scale * w[i]);
}

// ---------------------------------------------------------------------------
// RoPE kernels
// ---------------------------------------------------------------------------
__global__ __launch_bounds__(256) void rope_q16(unsigned short* __restrict__ q) {
    const int idx = blockIdx.x * 256 + threadIdx.x;
    if (idx >= S_LEN * NHEAD * (D_ROPE / 2)) return;
    const int i = idx & 31;
    const int h = (idx >> 5) & 31;
    const int s = idx >> 10;
    const float inv = __expf(-(float)i * (logf(10000.f) / 32.f));
    const float ang = (float)s * inv;
    const float cs = cosf(ang), sn = sinf(ang);
    unsigned short* p = q + (size_t)s * (NHEAD * D_QK) + h * D_QK + D_NOPE + 2 * i;
    const float x0 = b2f(p[0]), x1 = b2f(p[1]);
    p[0] = f2b(x0 * cs - x1 * sn);
    p[1] = f2b(x1 * cs + x0 * sn);
}

__global__ __launch_bounds__(256) void rope_k16(const float* __restrict__ C1,
                                                unsigned short* __restrict__ kpe16) {
    const int idx = blockIdx.x * 256 + threadIdx.x;
    if (idx >= S_LEN * (D_ROPE / 2)) return;
    const int i = idx & 31;
    const int s = idx >> 5;
    const float inv = __expf(-(float)i * (logf(10000.f) / 32.f));
    const float ang = (float)s * inv;
    const float cs = cosf(ang), sn = sinf(ang);
    const float* p = C1 + (size_t)s * 2176 + 2048 + 2 * i;
    const float x0 = p[0], x1 = p[1];
    kpe16[(size_t)s * D_ROPE + 2 * i] = f2b(x0 * cs - x1 * sn);
    kpe16[(size_t)s * D_ROPE + 2 * i + 1] = f2b(x1 * cs + x0 * sn);
}

// ---------------------------------------------------------------------------
// Indexer scores via split-bf16 MFMA. Tile 64q x 64k, lower-tri blocks only.
// iscore[q,k] = (1/sqrt(128)) * sum_n (iw[q,n]/4) * relu(iq[q,n,:].ik[k,:])
// LDS: ikh/ikl [64][128] swz @0/16384; iqh/iql @32768/49152; iw @65536
// ---------------------------------------------------------------------------
#define ISC_IKH 0
#define ISC_IKL 16384
#define ISC_IQH 32768
#define ISC_IQL 49152
#define ISC_IW 65536

__global__ __launch_bounds__(256) void idx_score_mfma(const unsigned short* __restrict__ iqh,
                                                      const unsigned short* __restrict__ iql,
                                                      const unsigned short* __restrict__ ikh,
                                                      const unsigned short* __restrict__ ikl,
                                                      const float* __restrict__ Cidx,
                                                      float* __restrict__ iscore) {
    const int kt = blockIdx.x, qt = blockIdx.y;
    if (kt > qt) return;
    const int q0 = qt * 64, k0 = kt * 64;
    __shared__ __align__(16) unsigned char smem[69632];
    const int tid = threadIdx.x;
    const int w = tid >> 6, lane = tid & 63;
    const int g = lane >> 4, lr = lane & 15;

    // stage ik hi/lo (swizzled) + iw
#pragma unroll
    for (int it = 0; it < 4; ++it) {
        const int j = tid + it * 256;
        const int row = j >> 4, slot = j & 15;
        const int dst = row * 256 + ((slot ^ (row & 7)) << 4);
        *(uint4*)(smem + ISC_IKH + dst) = *(const uint4*)(ikh + (size_t)(k0 + row) * 128 + slot * 8);
        *(uint4*)(smem + ISC_IKL + dst) = *(const uint4*)(ikl + (size_t)(k0 + row) * 128 + slot * 8);
    }
    {
        const int r = tid >> 2, c4 = (tid & 3) * 4;
        const float4 v = *(const float4*)(Cidx + (size_t)(q0 + r) * NIDX + 2176 + c4);
        float4 sv = {v.x * 0.25f, v.y * 0.25f, v.z * 0.25f, v.w * 0.25f};
        *(float4*)(smem + ISC_IW + r * 64 + c4 * 4) = sv;
    }

    f32x4 tot[4];
#pragma unroll
    for (int j = 0; j < 4; ++j) tot[j] = (f32x4){0.f, 0.f, 0.f, 0.f};

    for (int n = 0; n < IDXH; ++n) {
        __syncthreads();  // protect iq buffers (and ik/iw on first iter)
#pragma unroll
        for (int it = 0; it < 4; ++it) {
            const int j = tid + it * 256;
            const int row = j >> 4, slot = j & 15;
            const int dst = row * 256 + ((slot ^ (row & 7)) << 4);
            *(uint4*)(smem + ISC_IQH + dst) =
                *(const uint4*)(iqh + (size_t)(q0 + row) * 2048 + n * 128 + slot * 8);
            *(uint4*)(smem + ISC_IQL + dst) =
                *(const uint4*)(iql + (size_t)(q0 + row) * 2048 + n * 128 + slot * 8);
        }
        __syncthreads();

        bf16x8 aH[4], aL[4];
        const int ar = w * 16 + lr;
#pragma unroll
        for (int kk = 0; kk < 4; ++kk) {
            const int off = ar * 256 + (((kk * 4 + g) ^ (ar & 7)) << 4);
            aH[kk] = *(const bf16x8*)(smem + ISC_IQH + off);
            aL[kk] = *(const bf16x8*)(smem + ISC_IQL + off);
        }
        float wv[4];
#pragma unroll
        for (int r = 0; r < 4; ++r)
            wv[r] = *(const float*)(smem + ISC_IW + (w * 16 + g * 4 + r) * 64 + n * 4);

#pragma unroll
        for (int jj = 0; jj < 4; ++jj) {
            f32x4 s = (f32x4){0.f, 0.f, 0.f, 0.f};
#pragma unroll
            for (int kk = 0; kk < 4; ++kk) {
                const int br = jj * 16 + lr;
                const int off = br * 256 + (((kk * 4 + g) ^ (br & 7)) << 4);
                const bf16x8 bH = *(const bf16x8*)(smem + ISC_IKH + off);
                const bf16x8 bL = *(const bf16x8*)(smem + ISC_IKL + off);
                s = __builtin_amdgcn_mfma_f32_16x16x32_bf16(aH[kk], bH, s, 0, 0, 0);
                s = __builtin_amdgcn_mfma_f32_16x16x32_bf16(aH[kk], bL, s, 0, 0, 0);
                s = __builtin_amdgcn_mfma_f32_16x16x32_bf16(aL[kk], bH, s, 0, 0, 0);
            }
#pragma unroll
            for (int r = 0; r < 4; ++r) tot[jj][r] += wv[r] * fmaxf(s[r], 0.f);
        }
    }

    const float sc = 0.08838834764831845f;  // 1/sqrt(128)
#pragma unroll
    for (int jj = 0; jj < 4; ++jj)
#pragma unroll
        for (int r = 0; r < 4; ++r)
            iscore[(size_t)(q0 + w * 16 + g * 4 + r) * S_LEN + k0 + jj * 16 + lr] =
                tot[jj][r] * sc;
}

// ---------------------------------------------------------------------------
// Exact top-K per row (unchanged)
// ---------------------------------------------------------------------------
__global__ __launch_bounds__(256) void topk_kernel(const float* __restrict__ iscore,
                                                   unsigned char* __restrict__ mask) {
    const int q = blockIdx.x;
    const int tid = threadIdx.x;
    const int nk = q + 1;
    unsigned char* mrow = mask + (size_t)q * S_LEN;
    if (nk <= KSEL) {
        for (int k = tid; k < S_LEN; k += 256) mrow[k] = (k <= q) ? 1 : 0;
        return;
    }
    __shared__ unsigned int uv[S_LEN];
    const float* srow = iscore + (size_t)q * S_LEN;
    for (int k = tid; k < nk; k += 256) {
        unsigned int b = __float_as_uint(srow[k]);
        uv[k] = (b & 0x80000000u) ? ~b : (b | 0x80000000u);
    }
    __syncthreads();
    __shared__ int cnt;
    unsigned int lo = 0u, hi = 0xFFFFFFFFu;
    while (lo < hi) {
        const unsigned long long range = (unsigned long long)(hi - lo);
        const unsigned int mid = lo + (unsigned int)((range + 1ull) >> 1);
        if (tid == 0) cnt = 0;
        __syncthreads();
        int c = 0;
        for (int k = tid; k < nk; k += 256) c += (uv[k] >= mid) ? 1 : 0;
        atomicAdd(&cnt, c);
        __syncthreads();
        const int total = cnt;
        __syncthreads();
        if (total >= KSEL) lo = mid; else hi = mid - 1;
    }
    const unsigned int T = lo;
    if (tid == 0) cnt = 0;
    __syncthreads();
    {
        int c = 0;
        for (int k = tid; k < nk; k += 256) c += (uv[k] > T) ? 1 : 0;
        atomicAdd(&cnt, c);
    }
    __syncthreads();
    const int r = KSEL - cnt;
    for (int k = tid; k < S_LEN; k += 256) {
        unsigned char mv = 0;
        if (k < nk) {
            const unsigned int u = uv[k];
            if (u > T) {
                mv = 1;
            } else if (u == T) {
                int rank = 0;
                for (int j = 0; j < k; ++j) rank += (uv[j] == T) ? 1 : 0;
                mv = (rank < r) ? 1 : 0;
            }
        }
        mrow[k] = mv;
    }
}

// ---------------------------------------------------------------------------
// kb16[h][s][192] = {kv16[s][h*256+d] (d<128), kpe16[s][d-128]}
// ---------------------------------------------------------------------------
__global__ __launch_bounds__(256) void pack_k16(const unsigned short* __restrict__ kv16,
                                                const unsigned short* __restrict__ kpe16,
                                                unsigned short* __restrict__ kb16) {
    const int idx = blockIdx.x * 256 + threadIdx.x;
    const int h = idx / (S_LEN * D_QK);
    const int rem = idx - h * (S_LEN * D_QK);
    const int s = rem / D_QK;
    const int d = rem - s * D_QK;
    kb16[idx] = (d < 128) ? kv16[(size_t)s * 8192 + h * 256 + d]
                          : kpe16[(size_t)s * D_ROPE + (d - 128)];
}

__global__ __launch_bounds__(256) void pack_vT16(const unsigned short* __restrict__ kv16,
                                                 unsigned short* __restrict__ vT) {
    const int st = blockIdx.x, h = blockIdx.y;
    const int s0 = st * 64;
    __shared__ unsigned short lv[64][130];
    const int tid = threadIdx.x;
#pragma unroll
    for (int it = 0; it < 32; ++it) {
        const int idx = tid + it * 256;
        const int sl = idx >> 7, d = idx & 127;
        lv[sl][d] = kv16[(size_t)(s0 + sl) * 8192 + h * 256 + 128 + d];
    }
    __syncthreads();
#pragma unroll
    for (int it = 0; it < 32; ++it) {
        const int idx = tid + it * 256;
        const int d = idx >> 6, sl = idx & 63;
        vT[(size_t)(h * 128 + d) * S_LEN + s0 + sl] = lv[sl][d];
    }
}

// ---------------------------------------------------------------------------
// MFMA flash attention (as round 3)
// ---------------------------------------------------------------------------
#define ALD_K 0
#define ALD_V 12288
#define ALD_P 22528
#define ALD_M 27648

__global__ __launch_bounds__(256) void attn_mfma_kernel(
    const unsigned short* __restrict__ qbuf16,
    const unsigned short* __restrict__ kb16,
    const unsigned short* __restrict__ vT,
    const unsigned char* __restrict__ mask,
    unsigned short* __restrict__ ab16) {
    __shared__ __align__(16) unsigned char smem[29696];
    const int qt = blockIdx.x, h = blockIdx.y;
    const int q0 = qt * 64;
    const int tid = threadIdx.x;
    const int w = tid >> 6, lane = tid & 63;
    const int g = lane >> 4, lr = lane & 15;

    bf16x8 qf[6];
    {
        const unsigned short* qrow = qbuf16 + (size_t)(q0 + w * 16 + lr) * (NHEAD * D_QK) + h * D_QK;
#pragma unroll
        for (int c = 0; c < 6; ++c) qf[c] = *(const bf16x8*)(qrow + c * 32 + g * 8);
    }

    f32x4 O[8];
#pragma unroll
    for (int db = 0; db < 8; ++db) O[db] = (f32x4){0.f, 0.f, 0.f, 0.f};
    float mS[4] = {-INFINITY, -INFINITY, -INFINITY, -INFINITY};
    float lS[4] = {0.f, 0.f, 0.f, 0.f};

    const int nt = (q0 + 64) >> 5;
    const unsigned char* kbase = (const unsigned char*)(kb16 + (size_t)h * S_LEN * D_QK);
    const unsigned char* vbase = (const unsigned char*)(vT + (size_t)h * 128 * S_LEN);
    const unsigned char* mbase = mask + (size_t)q0 * S_LEN;
    unsigned short* Pb = (unsigned short*)(smem + ALD_P + w * 1280);

    for (int t = 0; t < nt; ++t) {
        const int k0 = t << 5;
#pragma unroll
        for (int it = 0; it < 3; ++it) {
            const int j = tid + it * 256;
            const int row = j / 24, cs = j - row * 24;
            const int colb = cs << 4;
            const uint4 v = *(const uint4*)(kbase + (size_t)(k0 + row) * 384 + colb);
            *(uint4*)(smem + ALD_K + row * 384 + (colb ^ ((row & 7) << 4))) = v;
        }
#pragma unroll
        for (int it = 0; it < 2; ++it) {
            const int j = tid + it * 256;
            const int d = j >> 2, slot = j & 3;
            const uint4 v = *(const uint4*)(vbase + ((size_t)d * S_LEN + k0) * 2 + slot * 16);
            *(uint4*)(smem + ALD_V + d * 80 + slot * 16) = v;
        }
        {
            const int qr = tid >> 2, kc = (tid & 3) << 3;
            const uint2 v = *(const uint2*)(mbase + (size_t)qr * S_LEN + k0 + kc);
            *(uint2*)(smem + ALD_M + qr * 32 + kc) = v;
        }
        __syncthreads();

        f32x4 a0 = (f32x4){0.f, 0.f, 0.f, 0.f};
        f32x4 a1 = (f32x4){0.f, 0.f, 0.f, 0.f};
#pragma unroll
        for (int c = 0; c < 6; ++c) {
            const int colb = c * 64 + g * 16;
            const bf16x8 b0 = *(const bf16x8*)(smem + ALD_K + lr * 384 + (colb ^ ((lr & 7) << 4)));
            const bf16x8 b1 = *(const bf16x8*)(smem + ALD_K + (16 + lr) * 384 + (colb ^ ((lr & 7) << 4)));
            a0 = __builtin_amdgcn_mfma_f32_16x16x32_bf16(qf[c], b0, a0, 0, 0, 0);
            a1 = __builtin_amdgcn_mfma_f32_16x16x32_bf16(qf[c], b1, a1, 0, 0, 0);
        }

        float corr[4];
#pragma unroll
        for (int r = 0; r < 4; ++r) {
            const int qrl = w * 16 + g * 4 + r;
            const float s0 = smem[ALD_M + qrl * 32 + lr] ? a0[r] : -INFINITY;
            const float s1 = smem[ALD_M + qrl * 32 + 16 + lr] ? a1[r] : -INFINITY;
            float tm = fmaxf(s0, s1);
            tm = fmaxf(tm, __shfl_xor(tm, 1));
            tm = fmaxf(tm, __shfl_xor(tm, 2));
            tm = fmaxf(tm, __shfl_xor(tm, 4));
            tm = fmaxf(tm, __shfl_xor(tm, 8));
            const float mn = fmaxf(mS[r], tm);
            const float co = (mS[r] > -INFINITY) ? __expf(mS[r] - mn) : 0.f;
            const float p0 = (s0 > -INFINITY) ? __expf(s0 - mn) : 0.f;
            const float p1 = (s1 > -INFINITY) ? __expf(s1 - mn) : 0.f;
            float rs = p0 + p1;
            rs += __shfl_xor(rs, 1);
            rs += __shfl_xor(rs, 2);
            rs += __shfl_xor(rs, 4);
            rs += __shfl_xor(rs, 8);
            lS[r] = lS[r] * co + rs;
            mS[r] = mn;
            corr[r] = co;
            Pb[(g * 4 + r) * 40 + lr] = f2b(p0);
            Pb[(g * 4 + r) * 40 + 16 + lr] = f2b(p1);
        }
#pragma unroll
        for (int db = 0; db < 8; ++db) {
            O[db][0] *= corr[0];
            O[db][1] *= corr[1];
            O[db][2] *= corr[2];
            O[db][3] *= corr[3];
        }

        asm volatile("s_waitcnt lgkmcnt(0)" ::: "memory");
        __builtin_amdgcn_sched_barrier(0);

        const bf16x8 pA = *(const bf16x8*)((const unsigned char*)Pb + lr * 80 + g * 16);
#pragma unroll
        for (int db = 0; db < 8; ++db) {
            const bf16x8 bV = *(const bf16x8*)(smem + ALD_V + (db * 16 + lr) * 80 + g * 16);
            O[db] = __builtin_amdgcn_mfma_f32_16x16x32_bf16(pA, bV, O[db], 0, 0, 0);
        }
        __syncthreads();
    }

#pragma unroll
    for (int r = 0; r < 4; ++r) {
        const float inv = (lS[r] > 0.f) ? 1.f / lS[r] : 0.f;
        const int qg = q0 + w * 16 + g * 4 + r;
        unsigned short* orow = ab16 + (size_t)qg * (NHEAD * D_V) + h * D_V;
#pragma unroll
        for (int db = 0; db < 8; ++db) orow[db * 16 + lr] = f2b(O[db][r] * inv);
    }
}

// ---------------------------------------------------------------------------
extern "C" void kernel_launch(void* const* d_in, const int* in_sizes, int n_in,
                              void* d_out, int out_size, void* d_ws, size_t ws_size,
                              hipStream_t stream) {
    const float* hidden        = (const float*)d_in[0];
    const float* q_a_w         = (const float*)d_in[1];
    const float* q_a_norm_w    = (const float*)d_in[2];
    const float* q_b_w         = (const float*)d_in[3];
    const float* kv_a_w        = (const float*)d_in[4];
    const float* kv_a_norm_w   = (const float*)d_in[5];
    const float* kv_b_w        = (const float*)d_in[6];
    const float* o_w           = (const float*)d_in[7];
    const float* idx_wq_w      = (const float*)d_in[8];
    const float* idx_wk_w      = (const float*)d_in[9];
    const float* idx_weights_w = (const float*)d_in[10];
    float* out = (float*)d_out;

    char* ws = (char*)d_ws;
    // Z_A @0 (33.6M): BtAll -> kv16 -> owT
    unsigned short* BtAll = (unsigned short*)(ws + 0);
    unsigned short* kv16  = (unsigned short*)(ws + 0);
    unsigned short* owT   = (unsigned short*)(ws + 0);
    // Z_B @33.6M (33.6M): h16(hi)+h_lo -> qbuf16
    unsigned short* h16    = (unsigned short*)(ws + 33554432);
    unsigned short* h_lo   = (unsigned short*)(ws + 50331648);
    unsigned short* qbuf16 = (unsigned short*)(ws + 33554432);
    // Z_C @67108864 (17.8M): C1 -> vT
    float* C1          = (float*)(ws + 67108864);
    unsigned short* vT = (unsigned short*)(ws + 67108864);
    // Z_D @84934656 (37.7M): BtIdx hi/lo -> kb16
    unsigned short* BtIdxH = (unsigned short*)(ws + 84934656);
    unsigned short* BtIdxL = (unsigned short*)(ws + 103809024);
    unsigned short* kb16   = (unsigned short*)(ws + 84934656);
    // Z_E @122683392 (18.9M): Cidx -> qbT
    float* Cidx         = (float*)(ws + 122683392);
    unsigned short* qbT = (unsigned short*)(ws + 122683392);
    // Z_F @141557760 (17.8M): iqh/iql/ikh/ikl -> kvbT
    unsigned short* iqh  = (unsigned short*)(ws + 141557760);
    unsigned short* iql  = (unsigned short*)(ws + 149946368);
    unsigned short* ikh  = (unsigned short*)(ws + 158334976);
    unsigned short* ikl  = (unsigned short*)(ws + 158859264);
    unsigned short* kvbT = (unsigned short*)(ws + 141557760);
    // Z_G @159383552 (16.8M): iscr -> ab16
    float* iscr          = (float*)(ws + 159383552);
    unsigned short* ab16 = (unsigned short*)(ws + 159383552);
    // Z_H/Z_I
    unsigned char* mask   = (unsigned char*)(ws + 176160768);
    unsigned short* qa16  = (unsigned short*)(ws + 180355072);
    unsigned short* kvn16 = (unsigned short*)(ws + 186646528);
    unsigned short* kpe16 = (unsigned short*)(ws + 188743680);
    (void)ws_size; (void)in_sizes; (void)n_in; (void)out_size;

    const dim3 blk(256);
    const float QK_SCALE = 0.07216878364870323f;  // 1/sqrt(192)

    // hidden -> hi/lo bf16
    conv_split_h<<<8192, blk, 0, stream>>>(hidden, h16, h_lo);

    // stage-1 fused (q_a | kv_a | pad) and C1 = h @ W
    wtrans<<<dim3(24, 64), blk, 0, stream>>>(q_a_w, BtAll, HIDDEN, QRANK);
    wtrans<<<dim3(9, 64), blk, 0, stream>>>(kv_a_w, BtAll + (size_t)1536 * HIDDEN, HIDDEN, KVRANK + D_ROPE);
    wtrans<<<dim3(1, 64), blk, 0, stream>>>(q_a_w, BtAll + (size_t)2112 * HIDDEN, HIDDEN, 0);  // zeros
    gemm_bf16<0><<<dim3(17, 16), blk, 0, stream>>>(h16, BtAll, C1, HIDDEN, 2176, 1.f);

    rmsnormb<<<S_LEN, blk, 0, stream>>>(C1, q_a_norm_w, qa16, QRANK, 2176);
    rmsnormb<<<S_LEN, blk, 0, stream>>>(C1 + 1536, kv_a_norm_w, kvn16, KVRANK, 2176);
    rope_k16<<<(S_LEN * 32 + 255) / 256, blk, 0, stream>>>(C1, kpe16);

    // indexer: fused split-precision GEMM (wq | wk | weights | pad)
    wtrans_split<<<dim3(32, 64), blk, 0, stream>>>(idx_wq_w, BtIdxH, BtIdxL, HIDDEN, IDXH * IDXD);
    wtrans_split<<<dim3(2, 64), blk, 0, stream>>>(idx_wk_w, BtIdxH + (size_t)2048 * HIDDEN,
                                                  BtIdxL + (size_t)2048 * HIDDEN, HIDDEN, IDXD);
    wtrans_split<<<dim3(2, 64), blk, 0, stream>>>(idx_weights_w, BtIdxH + (size_t)2176 * HIDDEN,
                                                  BtIdxL + (size_t)2176 * HIDDEN, HIDDEN, IDXH);
    gemm_split<<<dim3(18, 16), blk, 0, stream>>>(h16, h_lo, BtIdxH, BtIdxL, Cidx, HIDDEN, NIDX);
    conv_split_iq<<<4352, blk, 0, stream>>>(Cidx, iqh, iql, ikh, ikl);
    idx_score_mfma<<<dim3(32, 32), blk, 0, stream>>>(iqh, iql, ikh, ikl, Cidx, iscr);
    topk_kernel<<<S_LEN, blk, 0, stream>>>(iscr, mask);

    // stage-2 projections (h16/h_lo, Cidx, iq* dead now)
    wtrans<<<dim3(96, 24), blk, 0, stream>>>(q_b_w, qbT, QRANK, NHEAD * D_QK);
    wtrans<<<dim3(128, 8), blk, 0, stream>>>(kv_b_w, kvbT, KVRANK, NHEAD * 256);
    gemm_bf16<1><<<dim3(48, 16), blk, 0, stream>>>(qa16, qbT, qbuf16, QRANK, NHEAD * D_QK, QK_SCALE);
    gemm_bf16<1><<<dim3(64, 16), blk, 0, stream>>>(kvn16, kvbT, kv16, KVRANK, NHEAD * 256, 1.f);
    rope_q16<<<(S_LEN * NHEAD * 32 + 255) / 256, blk, 0, stream>>>(qbuf16);

    // attention
    pack_k16<<<(NHEAD * S_LEN * D_QK) / 256, blk, 0, stream>>>(kv16, kpe16, kb16);
    pack_vT16<<<dim3(S_LEN / 64, NHEAD), blk, 0, stream>>>(kv16, vT);
    attn_mfma_kernel<<<dim3(S_LEN / 64, NHEAD), blk, 0, stream>>>(qbuf16, kb16, vT, mask, ab16);

    // output projection
    wtrans<<<dim3(64, 64), blk, 0, stream>>>(o_w, owT, NHEAD * D_V, HIDDEN);
    gemm_bf16<0><<<dim3(32, 16), blk, 0, stream>>>(ab16, owT, out, NHEAD * D_V, HIDDEN, 1.f);
}